// Round 7
// baseline (278.032 us; speedup 1.0000x reference)
//
#include <hip/hip_runtime.h>
#include <hip/hip_bf16.h>

#define H_DIM 2048
#define B_SZ  8
#define SEQ   1024
#define M_DIM (B_SZ*SEQ)   // 8192
#define KDIM  2048
#define NKT   (KDIM/64)    // 32 K-tiles
#define CCH   32           // scan chunks
#define CLEN  (SEQ/CCH)    // 32 steps per chunk

using f32x4  = __attribute__((ext_vector_type(4))) float;
using f32x16 = __attribute__((ext_vector_type(16))) float;
using s16x8  = __attribute__((ext_vector_type(8))) short;

__device__ __forceinline__ float bf2f(unsigned short u) {
  unsigned int x = ((unsigned int)u) << 16;
  return __builtin_bit_cast(float, x);
}
__device__ __forceinline__ unsigned short f2bf(float f) {
  unsigned int x = __builtin_bit_cast(unsigned int, f);
  unsigned int r = (x + 0x7fffu + ((x >> 16) & 1u)) >> 16;
  return (unsigned short)r;
}

__device__ __forceinline__ void gl_lds16(const void* g, void* l) {
  __builtin_amdgcn_global_load_lds(
      (__attribute__((address_space(1))) void*)g,
      (__attribute__((address_space(3))) void*)l, 16, 0, 0);
}

// ---------------- transpose fp32 [R][C] -> bf16 [C][R] ----------------
__global__ __launch_bounds__(256) void transpose_kernel(
    const float* __restrict__ src, unsigned short* __restrict__ dst, int R, int C)
{
  __shared__ float t[32][33];
  int tx = threadIdx.x & 31, ty = threadIdx.x >> 5;
  int c0 = blockIdx.x << 5, r0 = blockIdx.y << 5;
#pragma unroll
  for (int i = 0; i < 32; i += 8)
    t[ty + i][tx] = src[(size_t)(r0 + ty + i) * C + (c0 + tx)];
  __syncthreads();
#pragma unroll
  for (int i = 0; i < 32; i += 8)
    dst[(size_t)(c0 + ty + i) * R + (r0 + tx)] = f2bf(t[tx][ty + i]);
}

// ---------------- LayerNorm + clip + delta (fused) ----------------
__global__ __launch_bounds__(256) void ln_delta_kernel(
    const float* __restrict__ x, const float* __restrict__ lns,
    const float* __restrict__ lnb, const float* __restrict__ dtk,
    const float* __restrict__ dtb, unsigned short* __restrict__ xn,
    float* __restrict__ delta)
{
  const int row = blockIdx.x;
  const int tid = threadIdx.x;
  const float* xr = x + (size_t)row * H_DIM;
  float v[8];
  *(float4*)&v[0] = ((const float4*)xr)[tid * 2];
  *(float4*)&v[4] = ((const float4*)xr)[tid * 2 + 1];
  float s1 = 0.f, s2 = 0.f;
#pragma unroll
  for (int j = 0; j < 8; ++j) { s1 += v[j]; s2 += v[j] * v[j]; }
  __shared__ float red[8];
#pragma unroll
  for (int off = 32; off; off >>= 1) {
    s1 += __shfl_down(s1, off);
    s2 += __shfl_down(s2, off);
  }
  if ((tid & 63) == 0) { red[tid >> 6] = s1; red[4 + (tid >> 6)] = s2; }
  __syncthreads();
  float mean = (red[0] + red[1] + red[2] + red[3]) * (1.0f / H_DIM);
  float var  = (red[4] + red[5] + red[6] + red[7]) * (1.0f / H_DIM) - mean * mean;
  float rstd = rsqrtf(var + 1e-6f);

  float sc[8], bi[8], dk[8];
  *(float4*)&sc[0] = ((const float4*)lns)[tid * 2];
  *(float4*)&sc[4] = ((const float4*)lns)[tid * 2 + 1];
  *(float4*)&bi[0] = ((const float4*)lnb)[tid * 2];
  *(float4*)&bi[4] = ((const float4*)lnb)[tid * 2 + 1];
  *(float4*)&dk[0] = ((const float4*)dtk)[tid * 2];
  *(float4*)&dk[4] = ((const float4*)dtk)[tid * 2 + 1];

  float dot = 0.f;
  s16x8 o;
#pragma unroll
  for (int j = 0; j < 8; ++j) {
    float xv = (v[j] - mean) * rstd * sc[j] + bi[j];
    xv = fminf(fmaxf(xv, -1.0e6f), 1.0e6f);
    dot += xv * dk[j];
    o[j] = (short)f2bf(xv);
  }
  *(s16x8*)(xn + (size_t)row * H_DIM + tid * 8) = o;

  __syncthreads();
#pragma unroll
  for (int off = 32; off; off >>= 1) dot += __shfl_down(dot, off);
  if ((tid & 63) == 0) red[tid >> 6] = dot;
  __syncthreads();
  if (tid == 0)
    delta[row] = __expf(red[0] + red[1] + red[2] + red[3] + dtb[0]);
}

// ---------------- chunked parallel scan ----------------
__global__ __launch_bounds__(256) void scan1_kernel(
    const unsigned short* __restrict__ U, const float* __restrict__ delta,
    const float* __restrict__ Adiag, float* __restrict__ Q, float* __restrict__ P)
{
  const int h = blockIdx.x * 1024 + threadIdx.x * 4;
  const int c = blockIdx.y, b = blockIdx.z;
  const float4 a = *(const float4*)(Adiag + h);
  const unsigned short* u = U + ((size_t)b * SEQ + c * CLEN) * H_DIM + h;
  const float* dl = delta + b * SEQ + c * CLEN;
  float4 st = {0.f, 0.f, 0.f, 0.f};
  float4 pr = {1.f, 1.f, 1.f, 1.f};
#pragma unroll 8
  for (int s = 0; s < CLEN; ++s) {
    const float d = dl[s];
    const ushort4 uv = *(const ushort4*)(u + (size_t)s * H_DIM);
    const float dx = __expf(d * a.x), dy = __expf(d * a.y);
    const float dz = __expf(d * a.z), dw = __expf(d * a.w);
    st.x = fmaf(st.x, dx, bf2f(uv.x)); st.y = fmaf(st.y, dy, bf2f(uv.y));
    st.z = fmaf(st.z, dz, bf2f(uv.z)); st.w = fmaf(st.w, dw, bf2f(uv.w));
    pr.x *= dx; pr.y *= dy; pr.z *= dz; pr.w *= dw;
  }
  const size_t idx = ((size_t)b * CCH + c) * H_DIM + h;
  *(float4*)(Q + idx) = st;
  *(float4*)(P + idx) = pr;
}

__global__ __launch_bounds__(256) void scan2_kernel(
    const float* __restrict__ Q, const float* __restrict__ P,
    const float* __restrict__ ctx, float* __restrict__ sIn,
    float* __restrict__ finalSt)
{
  const int h = blockIdx.x * 256 + threadIdx.x;
  const int b = blockIdx.y;
  float s = ctx[b * H_DIM + h];
#pragma unroll
  for (int c = 0; c < CCH; ++c) {
    const size_t idx = ((size_t)b * CCH + c) * H_DIM + h;
    sIn[idx] = s;
    s = fmaf(s, P[idx], Q[idx]);
  }
  finalSt[b * H_DIM + h] = s;
}

__global__ __launch_bounds__(256) void scan3_kernel(
    const unsigned short* __restrict__ U, const float* __restrict__ delta,
    const float* __restrict__ Adiag, const float* __restrict__ sIn,
    unsigned short* __restrict__ states)
{
  const int h = blockIdx.x * 1024 + threadIdx.x * 4;
  const int c = blockIdx.y, b = blockIdx.z;
  const float4 a = *(const float4*)(Adiag + h);
  const unsigned short* u = U + ((size_t)b * SEQ + c * CLEN) * H_DIM + h;
  unsigned short* so = states + ((size_t)b * SEQ + c * CLEN) * H_DIM + h;
  const float* dl = delta + b * SEQ + c * CLEN;
  float4 st = *(const float4*)(sIn + ((size_t)b * CCH + c) * H_DIM + h);
#pragma unroll 8
  for (int s = 0; s < CLEN; ++s) {
    const float d = dl[s];
    const ushort4 uv = *(const ushort4*)(u + (size_t)s * H_DIM);
    const float dx = __expf(d * a.x), dy = __expf(d * a.y);
    const float dz = __expf(d * a.z), dw = __expf(d * a.w);
    st.x = fmaf(st.x, dx, bf2f(uv.x)); st.y = fmaf(st.y, dy, bf2f(uv.y));
    st.z = fmaf(st.z, dz, bf2f(uv.z)); st.w = fmaf(st.w, dw, bf2f(uv.w));
    ushort4 ov = { f2bf(st.x), f2bf(st.y), f2bf(st.z), f2bf(st.w) };
    *(ushort4*)(so + (size_t)s * H_DIM) = ov;
  }
}

// ============ 256x256 8-phase GEMM, v_mfma_f32_32x32x16_bf16 ============
// Same staging/swizzle/vmcnt skeleton as round 6; fragments remapped for
// 32x32: wave rows (2mi+wr)*32 (aA always A-half0, aB always A-half1 for
// both wr), cols n*128+wc*32 (bA=B-half0, bB=B-half1 for all wc) -> every
// read trails its stage by >=4 stage-calls under VMC(6).
// EPI: 1 = bf16 out, 2 = GLU: out = Y * sigmoid(acc + gbias)  (f32 out)

#define BARR()  __builtin_amdgcn_s_barrier();
#define VMC(N)  asm volatile("s_waitcnt vmcnt(" #N ")" ::: "memory");

#define RD_AM(DST, BUF, MQ) { _Pragma("unroll") for (int m_ = 0; m_ < 2; ++m_) \
  _Pragma("unroll") for (int s_ = 0; s_ < 4; ++s_) \
    DST[m_][s_] = *(const s16x8*)(paA + (BUF) * 32768 + (MQ) * 16384 + m_ * 8192 + soff[s_]); }
#define RD_BN(DST, BUF, N) { _Pragma("unroll") for (int s_ = 0; s_ < 4; ++s_) \
    DST[s_] = *(const s16x8*)(pbB + (BUF) * 32768 + (N) * 16384 + soff[s_]); }

#define QMM(AF, BF, MI, NI) { __builtin_amdgcn_s_setprio(1); \
  _Pragma("unroll") for (int m_ = 0; m_ < 2; ++m_) \
  _Pragma("unroll") for (int s_ = 0; s_ < 4; ++s_) \
    acc[(MI)+m_][NI] = __builtin_amdgcn_mfma_f32_32x32x16_bf16(AF[m_][s_], BF[s_], acc[(MI)+m_][NI], 0, 0, 0); \
  __builtin_amdgcn_s_setprio(0); }

#define STAGE_A(BUF, HH, TT) { const char* s_ = srcA + (HH) * 524288 + (TT) * 128; \
  char* d_ = ldsA + (BUF) * 32768 + (HH) * 16384 + tid16; \
  gl_lds16(s_, d_); gl_lds16(s_ + 262144, d_ + 8192); }
#define STAGE_B(BUF, HH, TT) { const char* s_ = srcB + (HH) * 524288 + (TT) * 128; \
  char* d_ = ldsB + (BUF) * 32768 + (HH) * 16384 + tid16; \
  gl_lds16(s_, d_); gl_lds16(s_ + 262144, d_ + 8192); }

template <int EPI>
__global__ __launch_bounds__(512, 2) void gemm8p(
    const char* __restrict__ Ab, const char* __restrict__ Bb,
    float* __restrict__ outF, unsigned short* __restrict__ outH,
    const unsigned short* __restrict__ Ybf, const float* __restrict__ gbias)
{
  extern __shared__ char lds[];
  char* ldsA = lds;            // 2 bufs x 32KB
  char* ldsB = lds + 65536;    // 2 bufs x 32KB

  const int tid  = threadIdx.x;
  const int lane = tid & 63, wid = tid >> 6;
  const int wr = wid >> 2, wc = wid & 3;       // 2x4 wave grid
  const int ln31 = lane & 31, l5 = lane >> 5;

  // ---- XCD-grouped block swizzle: each XCD owns an 8(bm) x 4(bn) group ----
  const int bid = blockIdx.x;
  const int xcd = bid & 7;
  const int li  = bid >> 3;
  const int bm  = (xcd >> 1) * 8 + (li & 7);
  const int bn  = (xcd & 1) * 4 + (li >> 3);

  // ---- staging source (pre-swizzled global, linear LDS dest) ----
  const int grow = tid >> 3;
  const int gswz = ((tid & 7) ^ (grow & 7)) << 4;
  const char* srcA = Ab + ((size_t)(bm * 256 + grow)) * 4096 + gswz;
  const char* srcB = Bb + ((size_t)(bn * 256 + grow)) * 4096 + gswz;
  const int tid16 = tid << 4;

  // ---- ds_read bases + per-s swizzled granule offsets ----
  const char* paA = ldsA + wr * 4096 + ln31 * 128;   // + MQ*16384 + m*8192
  const char* pbB = ldsB + (wc * 32 + ln31) * 128;   // + N*16384
  int soff[4];
#pragma unroll
  for (int s = 0; s < 4; ++s)
    soff[s] = ((2 * s + l5) ^ (ln31 & 7)) << 4;

  f32x16 acc[4][2] = {};
  s16x8 aA[2][4], aB[2][4], bA[4], bB[4], bA2[4];

  // ---- prologue: stage T0 (4 halves) + T1 (3 halves) ----
  STAGE_A(0, 0, 0); STAGE_B(0, 0, 0); STAGE_B(0, 1, 0); STAGE_A(0, 1, 0);
  STAGE_A(1, 0, 1); STAGE_B(1, 0, 1); STAGE_B(1, 1, 1);
  VMC(6);
  BARR();
  RD_AM(aA, 0, 0);     // T0: m01 (A-half0)
  RD_BN(bA, 0, 0);     // T0: n0  (B-half0)

  // ---- main loop: 15 iters x 2 K-tiles (tiles 0..29) ----
  for (int t = 0; t < NKT / 2 - 1; ++t) {
    const int T0 = 2 * t;
    // P1
    RD_BN(bB, 0, 1);
    STAGE_A(1, 1, T0 + 1);
    QMM(aA, bA, 0, 0);
    VMC(6); BARR();
    // P2
    RD_AM(aB, 0, 1);
    STAGE_A(0, 0, T0 + 2);
    QMM(aA, bB, 0, 1);
    VMC(6); BARR();
    // P3
    RD_BN(bA2, 1, 0);
    STAGE_B(0, 0, T0 + 2);
    QMM(aB, bA, 2, 0);
    VMC(6); BARR();
    // P4
    RD_AM(aA, 1, 0);
    STAGE_B(0, 1, T0 + 2);
    QMM(aB, bB, 2, 1);
    VMC(6); BARR();
    // P5
    RD_BN(bB, 1, 1);
    STAGE_A(0, 1, T0 + 2);
    QMM(aA, bA2, 0, 0);
    VMC(6); BARR();
    // P6
    RD_AM(aB, 1, 1);
    STAGE_A(1, 0, T0 + 3);
    QMM(aA, bB, 0, 1);
    VMC(6); BARR();
    // P7
    RD_BN(bA, 0, 0);
    STAGE_B(1, 0, T0 + 3);
    QMM(aB, bA2, 2, 0);
    VMC(6); BARR();
    // P8
    RD_AM(aA, 0, 0);
    STAGE_B(1, 1, T0 + 3);
    QMM(aB, bB, 2, 1);
    VMC(6); BARR();
  }

  // ---- epilogue: tiles 30 (buf0) and 31 (buf1) ----
  RD_BN(bB, 0, 1);
  STAGE_A(1, 1, 31);
  QMM(aA, bA, 0, 0);
  VMC(6); BARR();
  RD_AM(aB, 0, 1);
  QMM(aA, bB, 0, 1);
  VMC(0); BARR();
  RD_BN(bA2, 1, 0);
  QMM(aB, bA, 2, 0);
  RD_AM(aA, 1, 0);
  QMM(aB, bB, 2, 1);
  RD_BN(bB, 1, 1);
  QMM(aA, bA2, 0, 0);
  RD_AM(aB, 1, 1);
  QMM(aA, bB, 0, 1);
  QMM(aB, bA2, 2, 0);
  QMM(aB, bB, 2, 1);

  // ---- LDS-staged coalesced C write ----
  // 32x32 C/D: rowin = (reg&3)+8*(reg>>2)+4*(lane>>5), col = lane&31
  // acc[mi][n]: row = (4*(mi>>1)+2*(mi&1)+wr)*32 + rowin, col = n*128+wc*32+ln31
  __syncthreads();
  if constexpr (EPI == 1) {
#pragma unroll
    for (int mi = 0; mi < 4; ++mi)
#pragma unroll
      for (int n = 0; n < 2; ++n)
#pragma unroll
        for (int reg = 0; reg < 16; ++reg) {
          const int rowin = (reg & 3) + 8 * (reg >> 2) + 4 * l5;
          const int row = (4 * (mi >> 1) + 2 * (mi & 1) + wr) * 32 + rowin;
          const int col = n * 128 + wc * 32 + ln31;
          const int off = (row * 512 + col * 2) ^ ((row & 7) << 4);
          *(unsigned short*)(lds + off) = f2bf(acc[mi][n][reg]);
        }
    __syncthreads();
#pragma unroll
    for (int it = 0; it < 16; ++it) {
      const int L = it * 8192 + tid * 16;
      const int row = L >> 9, inrow = L & 511;
      const s16x8 v = *(const s16x8*)(lds + (L ^ ((row & 7) << 4)));
      *(s16x8*)(outH + ((size_t)(bm * 256 + row)) * H_DIM + bn * 256 + (inrow >> 1)) = v;
    }
  } else {
    // GLU: two 128-row f32 passes; pass p holds acc[2p..2p+1][*]
#pragma unroll
    for (int p = 0; p < 2; ++p) {
      if (p) __syncthreads();
#pragma unroll
      for (int mi = 2 * p; mi < 2 * p + 2; ++mi)
#pragma unroll
        for (int n = 0; n < 2; ++n)
#pragma unroll
          for (int reg = 0; reg < 16; ++reg) {
            const int rowin = (reg & 3) + 8 * (reg >> 2) + 4 * l5;
            const int lrow = (2 * (mi & 1) + wr) * 32 + rowin;
            const int col = n * 128 + wc * 32 + ln31;
            const int off = (lrow * 1024 + col * 4) ^ ((lrow & 7) << 4);
            *(float*)(lds + off) = acc[mi][n][reg];
          }
      __syncthreads();
#pragma unroll
      for (int it = 0; it < 16; ++it) {
        const int L = it * 8192 + tid * 16;
        const int lrow = L >> 10, inrow = L & 1023;
        const f32x4 v = *(const f32x4*)(lds + (L ^ ((lrow & 7) << 4)));
        const size_t growg = (size_t)(bm * 256 + 128 * p + lrow);
        const int gcol = bn * 256 + (inrow >> 2);
        const float4 gb4 = *(const float4*)(gbias + gcol);
        const ushort4 y4 = *(const ushort4*)(Ybf + growg * H_DIM + gcol);
        float4 o;
        o.x = bf2f(y4.x) / (1.f + __expf(-(v[0] + gb4.x)));
        o.y = bf2f(y4.y) / (1.f + __expf(-(v[1] + gb4.y)));
        o.z = bf2f(y4.z) / (1.f + __expf(-(v[2] + gb4.z)));
        o.w = bf2f(y4.w) / (1.f + __expf(-(v[3] + gb4.w)));
        *(float4*)(outF + growg * H_DIM + gcol) = o;
      }
    }
  }
}

extern "C" void kernel_launch(void* const* d_in, const int* in_sizes, int n_in,
                              void* d_out, int out_size, void* d_ws, size_t ws_size,
                              hipStream_t stream) {
  (void)in_sizes; (void)n_in; (void)out_size; (void)ws_size;
  const float* x     = (const float*)d_in[0];
  const float* ctx   = (const float*)d_in[1];
  const float* Adiag = (const float*)d_in[2];
  const float* Bm    = (const float*)d_in[3];
  const float* Cm    = (const float*)d_in[4];
  const float* dtk   = (const float*)d_in[5];
  const float* dtb   = (const float*)d_in[6];
  const float* gk    = (const float*)d_in[7];
  const float* gb    = (const float*)d_in[8];
  const float* lns   = (const float*)d_in[9];
  const float* lnb   = (const float*)d_in[10];
  float* outF = (float*)d_out;

  char* ws = (char*)d_ws;
  unsigned short* xnY    = (unsigned short*)ws; ws += (size_t)M_DIM * H_DIM * 2;  // xn, later Y
  unsigned short* U      = (unsigned short*)ws; ws += (size_t)M_DIM * H_DIM * 2;
  unsigned short* states = (unsigned short*)ws; ws += (size_t)M_DIM * H_DIM * 2;
  unsigned short* T1     = (unsigned short*)ws; ws += (size_t)H_DIM * H_DIM * 2;
  unsigned short* T2     = (unsigned short*)ws; ws += (size_t)H_DIM * H_DIM * 2;
  unsigned short* T3     = (unsigned short*)ws; ws += (size_t)H_DIM * H_DIM * 2;
  float* delta           = (float*)ws;          ws += (size_t)M_DIM * 4;
  float* Qbuf            = (float*)ws;          ws += (size_t)B_SZ * CCH * H_DIM * 4;
  float* Pbuf            = (float*)ws;          ws += (size_t)B_SZ * CCH * H_DIM * 4;
  float* sInBuf          = (float*)ws;          ws += (size_t)B_SZ * CCH * H_DIM * 4;

  hipFuncSetAttribute((const void*)&gemm8p<1>,
                      hipFuncAttributeMaxDynamicSharedMemorySize, 131072);
  hipFuncSetAttribute((const void*)&gemm8p<2>,
                      hipFuncAttributeMaxDynamicSharedMemorySize, 131072);

  dim3 tb(256);
  transpose_kernel<<<dim3(64, 64), tb, 0, stream>>>(Bm, T1, H_DIM, H_DIM);
  transpose_kernel<<<dim3(64, 64), tb, 0, stream>>>(Cm, T2, H_DIM, H_DIM);
  transpose_kernel<<<dim3(64, 64), tb, 0, stream>>>(gk, T3, H_DIM, H_DIM);
  ln_delta_kernel<<<M_DIM, tb, 0, stream>>>(x, lns, lnb, dtk, dtb, xnY, delta);
  gemm8p<1><<<256, 512, 131072, stream>>>(
      (const char*)xnY, (const char*)T1, nullptr, U, nullptr, nullptr);
  scan1_kernel<<<dim3(H_DIM / 1024, CCH, B_SZ), tb, 0, stream>>>(
      U, delta, Adiag, Qbuf, Pbuf);
  scan2_kernel<<<dim3(H_DIM / 256, B_SZ), tb, 0, stream>>>(
      Qbuf, Pbuf, ctx, sInBuf, outF + (size_t)M_DIM * H_DIM);
  scan3_kernel<<<dim3(H_DIM / 1024, CCH, B_SZ), tb, 0, stream>>>(
      U, delta, Adiag, sInBuf, states);
  gemm8p<1><<<256, 512, 131072, stream>>>(
      (const char*)states, (const char*)T2, nullptr, xnY, nullptr, nullptr);
  gemm8p<2><<<256, 512, 131072, stream>>>(
      (const char*)xnY, (const char*)T3, outF, nullptr, xnY, gb);
}

// Round 8
// 256.978 us; speedup vs baseline: 1.0819x; 1.0819x over previous
//
#include <hip/hip_runtime.h>
#include <hip/hip_bf16.h>

#define H_DIM 2048
#define B_SZ  8
#define SEQ   1024
#define M_DIM (B_SZ*SEQ)   // 8192
#define KDIM  2048
#define NKT   (KDIM/64)    // 32 K-tiles
#define CCH   32           // scan chunks
#define CLEN  (SEQ/CCH)    // 32 steps per chunk

using f32x4 = __attribute__((ext_vector_type(4))) float;
using s16x8 = __attribute__((ext_vector_type(8))) short;

__device__ __forceinline__ float bf2f(unsigned short u) {
  unsigned int x = ((unsigned int)u) << 16;
  return __builtin_bit_cast(float, x);
}
__device__ __forceinline__ unsigned short f2bf(float f) {
  unsigned int x = __builtin_bit_cast(unsigned int, f);
  unsigned int r = (x + 0x7fffu + ((x >> 16) & 1u)) >> 16;
  return (unsigned short)r;
}

__device__ __forceinline__ void gl_lds16(const void* g, void* l) {
  __builtin_amdgcn_global_load_lds(
      (__attribute__((address_space(1))) void*)g,
      (__attribute__((address_space(3))) void*)l, 16, 0, 0);
}

// ------- fused transpose fp32 [2048][2048] -> bf16 [2048][2048]^T x3 -------
__global__ __launch_bounds__(256) void transpose3_kernel(
    const float* __restrict__ s0, unsigned short* __restrict__ d0,
    const float* __restrict__ s1, unsigned short* __restrict__ d1,
    const float* __restrict__ s2, unsigned short* __restrict__ d2)
{
  const float* src = (blockIdx.z == 0) ? s0 : (blockIdx.z == 1) ? s1 : s2;
  unsigned short* dst = (blockIdx.z == 0) ? d0 : (blockIdx.z == 1) ? d1 : d2;
  __shared__ float t[32][33];
  int tx = threadIdx.x & 31, ty = threadIdx.x >> 5;
  int c0 = blockIdx.x << 5, r0 = blockIdx.y << 5;
#pragma unroll
  for (int i = 0; i < 32; i += 8)
    t[ty + i][tx] = src[(size_t)(r0 + ty + i) * H_DIM + (c0 + tx)];
  __syncthreads();
#pragma unroll
  for (int i = 0; i < 32; i += 8)
    dst[(size_t)(c0 + ty + i) * H_DIM + (r0 + tx)] = f2bf(t[tx][ty + i]);
}

// ---------------- LayerNorm + clip + delta (fused) ----------------
__global__ __launch_bounds__(256) void ln_delta_kernel(
    const float* __restrict__ x, const float* __restrict__ lns,
    const float* __restrict__ lnb, const float* __restrict__ dtk,
    const float* __restrict__ dtb, unsigned short* __restrict__ xn,
    float* __restrict__ delta)
{
  const int row = blockIdx.x;
  const int tid = threadIdx.x;
  const float* xr = x + (size_t)row * H_DIM;
  float v[8];
  *(float4*)&v[0] = ((const float4*)xr)[tid * 2];
  *(float4*)&v[4] = ((const float4*)xr)[tid * 2 + 1];
  float s1 = 0.f, s2 = 0.f;
#pragma unroll
  for (int j = 0; j < 8; ++j) { s1 += v[j]; s2 += v[j] * v[j]; }
  __shared__ float red[8];
#pragma unroll
  for (int off = 32; off; off >>= 1) {
    s1 += __shfl_down(s1, off);
    s2 += __shfl_down(s2, off);
  }
  if ((tid & 63) == 0) { red[tid >> 6] = s1; red[4 + (tid >> 6)] = s2; }
  __syncthreads();
  float mean = (red[0] + red[1] + red[2] + red[3]) * (1.0f / H_DIM);
  float var  = (red[4] + red[5] + red[6] + red[7]) * (1.0f / H_DIM) - mean * mean;
  float rstd = rsqrtf(var + 1e-6f);

  float sc[8], bi[8], dk[8];
  *(float4*)&sc[0] = ((const float4*)lns)[tid * 2];
  *(float4*)&sc[4] = ((const float4*)lns)[tid * 2 + 1];
  *(float4*)&bi[0] = ((const float4*)lnb)[tid * 2];
  *(float4*)&bi[4] = ((const float4*)lnb)[tid * 2 + 1];
  *(float4*)&dk[0] = ((const float4*)dtk)[tid * 2];
  *(float4*)&dk[4] = ((const float4*)dtk)[tid * 2 + 1];

  float dot = 0.f;
  s16x8 o;
#pragma unroll
  for (int j = 0; j < 8; ++j) {
    float xv = (v[j] - mean) * rstd * sc[j] + bi[j];
    xv = fminf(fmaxf(xv, -1.0e6f), 1.0e6f);
    dot += xv * dk[j];
    o[j] = (short)f2bf(xv);
  }
  *(s16x8*)(xn + (size_t)row * H_DIM + tid * 8) = o;

  __syncthreads();
#pragma unroll
  for (int off = 32; off; off >>= 1) dot += __shfl_down(dot, off);
  if ((tid & 63) == 0) red[tid >> 6] = dot;
  __syncthreads();
  if (tid == 0)
    delta[row] = __expf(red[0] + red[1] + red[2] + red[3] + dtb[0]);
}

// ---------------- chunked parallel scan ----------------
__global__ __launch_bounds__(256) void scan1_kernel(
    const unsigned short* __restrict__ U, const float* __restrict__ delta,
    const float* __restrict__ Adiag, float* __restrict__ Q, float* __restrict__ P)
{
  const int h = blockIdx.x * 1024 + threadIdx.x * 4;
  const int c = blockIdx.y, b = blockIdx.z;
  const float4 a = *(const float4*)(Adiag + h);
  const unsigned short* u = U + ((size_t)b * SEQ + c * CLEN) * H_DIM + h;
  const float* dl = delta + b * SEQ + c * CLEN;
  float4 st = {0.f, 0.f, 0.f, 0.f};
  float4 pr = {1.f, 1.f, 1.f, 1.f};
#pragma unroll 8
  for (int s = 0; s < CLEN; ++s) {
    const float d = dl[s];
    const ushort4 uv = *(const ushort4*)(u + (size_t)s * H_DIM);
    const float dx = __expf(d * a.x), dy = __expf(d * a.y);
    const float dz = __expf(d * a.z), dw = __expf(d * a.w);
    st.x = fmaf(st.x, dx, bf2f(uv.x)); st.y = fmaf(st.y, dy, bf2f(uv.y));
    st.z = fmaf(st.z, dz, bf2f(uv.z)); st.w = fmaf(st.w, dw, bf2f(uv.w));
    pr.x *= dx; pr.y *= dy; pr.z *= dz; pr.w *= dw;
  }
  const size_t idx = ((size_t)b * CCH + c) * H_DIM + h;
  *(float4*)(Q + idx) = st;
  *(float4*)(P + idx) = pr;
}

__global__ __launch_bounds__(256) void scan2_kernel(
    const float* __restrict__ Q, const float* __restrict__ P,
    const float* __restrict__ ctx, float* __restrict__ sIn,
    float* __restrict__ finalSt)
{
  const int h = blockIdx.x * 256 + threadIdx.x;
  const int b = blockIdx.y;
  float s = ctx[b * H_DIM + h];
#pragma unroll
  for (int c = 0; c < CCH; ++c) {
    const size_t idx = ((size_t)b * CCH + c) * H_DIM + h;
    sIn[idx] = s;
    s = fmaf(s, P[idx], Q[idx]);
  }
  finalSt[b * H_DIM + h] = s;
}

__global__ __launch_bounds__(256) void scan3_kernel(
    const unsigned short* __restrict__ U, const float* __restrict__ delta,
    const float* __restrict__ Adiag, const float* __restrict__ sIn,
    unsigned short* __restrict__ states)
{
  const int h = blockIdx.x * 1024 + threadIdx.x * 4;
  const int c = blockIdx.y, b = blockIdx.z;
  const float4 a = *(const float4*)(Adiag + h);
  const unsigned short* u = U + ((size_t)b * SEQ + c * CLEN) * H_DIM + h;
  unsigned short* so = states + ((size_t)b * SEQ + c * CLEN) * H_DIM + h;
  const float* dl = delta + b * SEQ + c * CLEN;
  float4 st = *(const float4*)(sIn + ((size_t)b * CCH + c) * H_DIM + h);
#pragma unroll 8
  for (int s = 0; s < CLEN; ++s) {
    const float d = dl[s];
    const ushort4 uv = *(const ushort4*)(u + (size_t)s * H_DIM);
    const float dx = __expf(d * a.x), dy = __expf(d * a.y);
    const float dz = __expf(d * a.z), dw = __expf(d * a.w);
    st.x = fmaf(st.x, dx, bf2f(uv.x)); st.y = fmaf(st.y, dy, bf2f(uv.y));
    st.z = fmaf(st.z, dz, bf2f(uv.z)); st.w = fmaf(st.w, dw, bf2f(uv.w));
    ushort4 ov = { f2bf(st.x), f2bf(st.y), f2bf(st.z), f2bf(st.w) };
    *(ushort4*)(so + (size_t)s * H_DIM) = ov;
  }
}

// ===================== 256x256 8-phase bf16 GEMM (round-6 best) ==========
// Read-ahead pipelined 16x16x32: each phase issues ds_reads for the NEXT
// phase's fragments (overlap MFMA on LDS pipe); compiler places counted
// lgkmcnt; one s_barrier/phase with per-wave vmcnt(6) rolling certification.
// XCD-grouped blocks, XOR-swizzled LDS, LDS-staged coalesced epilogue.
// EPI: 1 = bf16 out, 2 = GLU: out = Y * sigmoid(acc + gbias)  (f32 out)

#define BARR()  __builtin_amdgcn_s_barrier();
#define VMC(N)  asm volatile("s_waitcnt vmcnt(" #N ")" ::: "memory");

#define RD_A(DST, PL, PHH, OFF) { _Pragma("unroll") for (int i_ = 0; i_ < 4; ++i_) { \
    DST[0][i_] = *(const s16x8*)((PL) + (OFF) + i_ * 4096); \
    DST[1][i_] = *(const s16x8*)((PHH) + (OFF) + i_ * 4096); } }
#define RD_B(DST, PL, PHH, OFF) { _Pragma("unroll") for (int j_ = 0; j_ < 2; ++j_) { \
    DST[0][j_] = *(const s16x8*)((PL) + (OFF) + j_ * 8192); \
    DST[1][j_] = *(const s16x8*)((PHH) + (OFF) + j_ * 8192); } }

#define QMM(IB, JB, AF, BF) { __builtin_amdgcn_s_setprio(1); \
  _Pragma("unroll") for (int i_ = 0; i_ < 4; ++i_) \
  _Pragma("unroll") for (int j_ = 0; j_ < 2; ++j_) { \
    acc[(IB)+i_][(JB)+j_] = __builtin_amdgcn_mfma_f32_16x16x32_bf16(AF[0][i_], BF[0][j_], acc[(IB)+i_][(JB)+j_], 0, 0, 0); \
    acc[(IB)+i_][(JB)+j_] = __builtin_amdgcn_mfma_f32_16x16x32_bf16(AF[1][i_], BF[1][j_], acc[(IB)+i_][(JB)+j_], 0, 0, 0); } \
  __builtin_amdgcn_s_setprio(0); }

#define STAGE_A(BUF, HH, TT) { const char* s_ = srcA + (HH) * 524288 + (TT) * 128; \
  char* d_ = ldsA + (BUF) * 32768 + (HH) * 16384 + tid16; \
  gl_lds16(s_, d_); gl_lds16(s_ + 262144, d_ + 8192); }
#define STAGE_B(BUF, HH, TT) { const char* s_ = srcB + (HH) * 524288 + (TT) * 128; \
  char* d_ = ldsB + (BUF) * 32768 + (HH) * 16384 + tid16; \
  gl_lds16(s_, d_); gl_lds16(s_ + 262144, d_ + 8192); }

template <int EPI>
__global__ __launch_bounds__(512, 2) void gemm8p(
    const char* __restrict__ Ab, const char* __restrict__ Bb,
    float* __restrict__ outF, unsigned short* __restrict__ outH,
    const unsigned short* __restrict__ Ybf, const float* __restrict__ gbias)
{
  extern __shared__ char lds[];
  char* ldsA = lds;            // 2 bufs x 32KB
  char* ldsB = lds + 65536;    // 2 bufs x 32KB

  const int tid  = threadIdx.x;
  const int lane = tid & 63, wid = tid >> 6;
  const int wr = wid >> 2, wc = wid & 3;       // 2x4 wave grid
  const int fr = lane & 15, kq = lane >> 4;

  // ---- XCD-grouped block swizzle: each XCD owns an 8(bm) x 4(bn) group ----
  const int bid = blockIdx.x;
  const int xcd = bid & 7;
  const int li  = bid >> 3;
  const int bm  = (xcd >> 1) * 8 + (li & 7);
  const int bn  = (xcd & 1) * 4 + (li >> 3);

  // ---- staging source (pre-swizzled global, linear LDS dest) ----
  const int grow = tid >> 3;
  const int gswz = ((tid & 7) ^ (grow & 7)) << 4;
  const char* srcA = Ab + ((size_t)(bm * 256 + grow)) * 4096 + gswz;
  const char* srcB = Bb + ((size_t)(bn * 256 + grow)) * 4096 + gswz;
  const int tid16 = tid << 4;

  // ---- swizzled ds_read base pointers ----
  const int sw0 = ((kq ^ (fr & 7)) << 4);
  const int sw1 = (((4 | kq) ^ (fr & 7)) << 4);
  const char* pa0b0 = ldsA + wr * 2048 + fr * 128 + sw0;
  const char* pa1b0 = ldsA + wr * 2048 + fr * 128 + sw1;
  const char* pa0b1 = pa0b0 + 32768;
  const char* pa1b1 = pa1b0 + 32768;
  const char* pb0b0 = ldsB + wc * 2048 + fr * 128 + sw0;
  const char* pb1b0 = ldsB + wc * 2048 + fr * 128 + sw1;
  const char* pb0b1 = pb0b0 + 32768;
  const char* pb1b1 = pb1b0 + 32768;

  f32x4 acc[8][4] = {};
  s16x8 a03[2][4], a47[2][4], b01a[2][2], b01b[2][2], b23[2][2];

  // ---- prologue: stage T0 (4 halves) + T1 (3 halves) ----
  STAGE_A(0, 0, 0); STAGE_B(0, 0, 0); STAGE_B(0, 1, 0); STAGE_A(0, 1, 0);
  STAGE_A(1, 0, 1); STAGE_B(1, 0, 1); STAGE_B(1, 1, 1);
  VMC(6);
  BARR();
  RD_A(a03, pa0b0, pa1b0, 0);
  RD_B(b01a, pb0b0, pb1b0, 0);

  // ---- main loop: 15 iters x 2 K-tiles (tiles 0..29) ----
  for (int t = 0; t < NKT / 2 - 1; ++t) {
    const int T0 = 2 * t;
    RD_B(b23, pb0b0, pb1b0, 16384);
    STAGE_A(1, 1, T0 + 1);
    QMM(0, 0, a03, b01a);
    VMC(6); BARR();
    RD_A(a47, pa0b0, pa1b0, 16384);
    STAGE_A(0, 0, T0 + 2);
    QMM(0, 2, a03, b23);
    VMC(6); BARR();
    RD_B(b01b, pb0b1, pb1b1, 0);
    STAGE_B(0, 0, T0 + 2);
    QMM(4, 0, a47, b01a);
    VMC(6); BARR();
    RD_A(a03, pa0b1, pa1b1, 0);
    STAGE_B(0, 1, T0 + 2);
    QMM(4, 2, a47, b23);
    VMC(6); BARR();
    RD_B(b23, pb0b1, pb1b1, 16384);
    STAGE_A(0, 1, T0 + 2);
    QMM(0, 0, a03, b01b);
    VMC(6); BARR();
    RD_A(a47, pa0b1, pa1b1, 16384);
    STAGE_A(1, 0, T0 + 3);
    QMM(0, 2, a03, b23);
    VMC(6); BARR();
    RD_B(b01a, pb0b0, pb1b0, 0);
    STAGE_B(1, 0, T0 + 3);
    QMM(4, 0, a47, b01b);
    VMC(6); BARR();
    RD_A(a03, pa0b0, pa1b0, 0);
    STAGE_B(1, 1, T0 + 3);
    QMM(4, 2, a47, b23);
    VMC(6); BARR();
  }

  // ---- epilogue: tiles 30 (buf0) and 31 (buf1) ----
  RD_B(b23, pb0b0, pb1b0, 16384);
  STAGE_A(1, 1, 31);
  QMM(0, 0, a03, b01a);
  VMC(6); BARR();
  RD_A(a47, pa0b0, pa1b0, 16384);
  QMM(0, 2, a03, b23);
  VMC(0); BARR();
  RD_B(b01b, pb0b1, pb1b1, 0);
  QMM(4, 0, a47, b01a);
  RD_A(a03, pa0b1, pa1b1, 0);
  QMM(4, 2, a47, b23);
  RD_B(b23, pb0b1, pb1b1, 16384);
  QMM(0, 0, a03, b01b);
  RD_A(a47, pa0b1, pa1b1, 16384);
  QMM(0, 2, a03, b23);
  QMM(4, 0, a47, b01b);
  QMM(4, 2, a47, b23);

  // ---- LDS-staged coalesced C write ----
  __syncthreads();
  const int cr = (lane >> 4) << 2;
  const int cc = lane & 15;
  if constexpr (EPI == 1) {
#pragma unroll
    for (int i = 0; i < 8; ++i)
#pragma unroll
      for (int j = 0; j < 4; ++j)
#pragma unroll
        for (int r = 0; r < 4; ++r) {
          const int row = (2 * i + wr) * 16 + cr + r;
          const int col = (4 * j + wc) * 16 + cc;
          const int off = (row * 512 + col * 2) ^ ((row & 7) << 4);
          *(unsigned short*)(lds + off) = f2bf(acc[i][j][r]);
        }
    __syncthreads();
#pragma unroll
    for (int it = 0; it < 16; ++it) {
      const int L = it * 8192 + tid * 16;
      const int row = L >> 9, inrow = L & 511;
      const s16x8 v = *(const s16x8*)(lds + (L ^ ((row & 7) << 4)));
      *(s16x8*)(outH + ((size_t)(bm * 256 + row)) * H_DIM + bn * 256 + (inrow >> 1)) = v;
    }
  } else {
#pragma unroll
    for (int p = 0; p < 2; ++p) {
      if (p) __syncthreads();
#pragma unroll
      for (int i = 4 * p; i < 4 * p + 4; ++i)
#pragma unroll
        for (int j = 0; j < 4; ++j)
#pragma unroll
          for (int r = 0; r < 4; ++r) {
            const int lrow = (2 * i + wr) * 16 + cr + r - 128 * p;
            const int col = (4 * j + wc) * 16 + cc;
            const int off = (lrow * 1024 + col * 4) ^ ((lrow & 7) << 4);
            *(float*)(lds + off) = acc[i][j][r];
          }
      __syncthreads();
#pragma unroll
      for (int it = 0; it < 16; ++it) {
        const int L = it * 8192 + tid * 16;
        const int lrow = L >> 10, inrow = L & 1023;
        const f32x4 v = *(const f32x4*)(lds + (L ^ ((lrow & 7) << 4)));
        const size_t growg = (size_t)(bm * 256 + 128 * p + lrow);
        const int gcol = bn * 256 + (inrow >> 2);
        const float4 gb4 = *(const float4*)(gbias + gcol);
        const ushort4 y4 = *(const ushort4*)(Ybf + growg * H_DIM + gcol);
        float4 o;
        o.x = bf2f(y4.x) / (1.f + __expf(-(v[0] + gb4.x)));
        o.y = bf2f(y4.y) / (1.f + __expf(-(v[1] + gb4.y)));
        o.z = bf2f(y4.z) / (1.f + __expf(-(v[2] + gb4.z)));
        o.w = bf2f(y4.w) / (1.f + __expf(-(v[3] + gb4.w)));
        *(float4*)(outF + growg * H_DIM + gcol) = o;
      }
    }
  }
}

extern "C" void kernel_launch(void* const* d_in, const int* in_sizes, int n_in,
                              void* d_out, int out_size, void* d_ws, size_t ws_size,
                              hipStream_t stream) {
  (void)in_sizes; (void)n_in; (void)out_size; (void)ws_size;
  const float* x     = (const float*)d_in[0];
  const float* ctx   = (const float*)d_in[1];
  const float* Adiag = (const float*)d_in[2];
  const float* Bm    = (const float*)d_in[3];
  const float* Cm    = (const float*)d_in[4];
  const float* dtk   = (const float*)d_in[5];
  const float* dtb   = (const float*)d_in[6];
  const float* gk    = (const float*)d_in[7];
  const float* gb    = (const float*)d_in[8];
  const float* lns   = (const float*)d_in[9];
  const float* lnb   = (const float*)d_in[10];
  float* outF = (float*)d_out;

  char* ws = (char*)d_ws;
  unsigned short* xnY    = (unsigned short*)ws; ws += (size_t)M_DIM * H_DIM * 2;  // xn, later Y
  unsigned short* U      = (unsigned short*)ws; ws += (size_t)M_DIM * H_DIM * 2;
  unsigned short* states = (unsigned short*)ws; ws += (size_t)M_DIM * H_DIM * 2;
  unsigned short* T1     = (unsigned short*)ws; ws += (size_t)H_DIM * H_DIM * 2;
  unsigned short* T2     = (unsigned short*)ws; ws += (size_t)H_DIM * H_DIM * 2;
  unsigned short* T3     = (unsigned short*)ws; ws += (size_t)H_DIM * H_DIM * 2;
  float* delta           = (float*)ws;          ws += (size_t)M_DIM * 4;
  float* Qbuf            = (float*)ws;          ws += (size_t)B_SZ * CCH * H_DIM * 4;
  float* Pbuf            = (float*)ws;          ws += (size_t)B_SZ * CCH * H_DIM * 4;
  float* sInBuf          = (float*)ws;          ws += (size_t)B_SZ * CCH * H_DIM * 4;

  hipFuncSetAttribute((const void*)&gemm8p<1>,
                      hipFuncAttributeMaxDynamicSharedMemorySize, 131072);
  hipFuncSetAttribute((const void*)&gemm8p<2>,
                      hipFuncAttributeMaxDynamicSharedMemorySize, 131072);

  dim3 tb(256);
  transpose3_kernel<<<dim3(64, 64, 3), tb, 0, stream>>>(Bm, T1, Cm, T2, gk, T3);
  ln_delta_kernel<<<M_DIM, tb, 0, stream>>>(x, lns, lnb, dtk, dtb, xnY, delta);
  gemm8p<1><<<256, 512, 131072, stream>>>(
      (const char*)xnY, (const char*)T1, nullptr, U, nullptr, nullptr);
  scan1_kernel<<<dim3(H_DIM / 1024, CCH, B_SZ), tb, 0, stream>>>(
      U, delta, Adiag, Qbuf, Pbuf);
  scan2_kernel<<<dim3(H_DIM / 256, B_SZ), tb, 0, stream>>>(
      Qbuf, Pbuf, ctx, sInBuf, outF + (size_t)M_DIM * H_DIM);
  scan3_kernel<<<dim3(H_DIM / 1024, CCH, B_SZ), tb, 0, stream>>>(
      U, delta, Adiag, sInBuf, states);
  gemm8p<1><<<256, 512, 131072, stream>>>(
      (const char*)states, (const char*)T2, nullptr, xnY, nullptr, nullptr);
  gemm8p<2><<<256, 512, 131072, stream>>>(
      (const char*)xnY, (const char*)T3, outF, nullptr, xnY, gb);
}

// Round 10
// 252.515 us; speedup vs baseline: 1.1011x; 1.0177x over previous
//
#include <hip/hip_runtime.h>
#include <hip/hip_bf16.h>

#define H_DIM 2048
#define B_SZ  8
#define SEQ   1024
#define M_DIM (B_SZ*SEQ)   // 8192
#define KDIM  2048
#define NKT   (KDIM/64)    // 32 K-tiles
#define CCH   32           // scan chunks
#define CLEN  (SEQ/CCH)    // 32 steps per chunk

using f32x4 = __attribute__((ext_vector_type(4))) float;
using s16x8 = __attribute__((ext_vector_type(8))) short;

__device__ __forceinline__ float bf2f(unsigned short u) {
  unsigned int x = ((unsigned int)u) << 16;
  return __builtin_bit_cast(float, x);
}
__device__ __forceinline__ unsigned short f2bf(float f) {
  unsigned int x = __builtin_bit_cast(unsigned int, f);
  unsigned int r = (x + 0x7fffu + ((x >> 16) & 1u)) >> 16;
  return (unsigned short)r;
}

__device__ __forceinline__ void gl_lds16(const void* g, void* l) {
  __builtin_amdgcn_global_load_lds(
      (__attribute__((address_space(1))) void*)g,
      (__attribute__((address_space(3))) void*)l, 16, 0, 0);
}

// ------- fused transpose fp32 [2048][2048] -> bf16 [2048][2048]^T x3 -------
__global__ __launch_bounds__(256) void transpose3_kernel(
    const float* __restrict__ s0, unsigned short* __restrict__ d0,
    const float* __restrict__ s1, unsigned short* __restrict__ d1,
    const float* __restrict__ s2, unsigned short* __restrict__ d2)
{
  const float* src = (blockIdx.z == 0) ? s0 : (blockIdx.z == 1) ? s1 : s2;
  unsigned short* dst = (blockIdx.z == 0) ? d0 : (blockIdx.z == 1) ? d1 : d2;
  __shared__ float t[32][33];
  int tx = threadIdx.x & 31, ty = threadIdx.x >> 5;
  int c0 = blockIdx.x << 5, r0 = blockIdx.y << 5;
#pragma unroll
  for (int i = 0; i < 32; i += 8)
    t[ty + i][tx] = src[(size_t)(r0 + ty + i) * H_DIM + (c0 + tx)];
  __syncthreads();
#pragma unroll
  for (int i = 0; i < 32; i += 8)
    dst[(size_t)(c0 + ty + i) * H_DIM + (r0 + tx)] = f2bf(t[tx][ty + i]);
}

// ---------------- LayerNorm + clip + delta (fused) ----------------
__global__ __launch_bounds__(256) void ln_delta_kernel(
    const float* __restrict__ x, const float* __restrict__ lns,
    const float* __restrict__ lnb, const float* __restrict__ dtk,
    const float* __restrict__ dtb, unsigned short* __restrict__ xn,
    float* __restrict__ delta)
{
  const int row = blockIdx.x;
  const int tid = threadIdx.x;
  const float* xr = x + (size_t)row * H_DIM;
  float v[8];
  *(float4*)&v[0] = ((const float4*)xr)[tid * 2];
  *(float4*)&v[4] = ((const float4*)xr)[tid * 2 + 1];
  float s1 = 0.f, s2 = 0.f;
#pragma unroll
  for (int j = 0; j < 8; ++j) { s1 += v[j]; s2 += v[j] * v[j]; }
  __shared__ float red[8];
#pragma unroll
  for (int off = 32; off; off >>= 1) {
    s1 += __shfl_down(s1, off);
    s2 += __shfl_down(s2, off);
  }
  if ((tid & 63) == 0) { red[tid >> 6] = s1; red[4 + (tid >> 6)] = s2; }
  __syncthreads();
  float mean = (red[0] + red[1] + red[2] + red[3]) * (1.0f / H_DIM);
  float var  = (red[4] + red[5] + red[6] + red[7]) * (1.0f / H_DIM) - mean * mean;
  float rstd = rsqrtf(var + 1e-6f);

  float sc[8], bi[8], dk[8];
  *(float4*)&sc[0] = ((const float4*)lns)[tid * 2];
  *(float4*)&sc[4] = ((const float4*)lns)[tid * 2 + 1];
  *(float4*)&bi[0] = ((const float4*)lnb)[tid * 2];
  *(float4*)&bi[4] = ((const float4*)lnb)[tid * 2 + 1];
  *(float4*)&dk[0] = ((const float4*)dtk)[tid * 2];
  *(float4*)&dk[4] = ((const float4*)dtk)[tid * 2 + 1];

  float dot = 0.f;
  s16x8 o;
#pragma unroll
  for (int j = 0; j < 8; ++j) {
    float xv = (v[j] - mean) * rstd * sc[j] + bi[j];
    xv = fminf(fmaxf(xv, -1.0e6f), 1.0e6f);
    dot += xv * dk[j];
    o[j] = (short)f2bf(xv);
  }
  *(s16x8*)(xn + (size_t)row * H_DIM + tid * 8) = o;

  __syncthreads();
#pragma unroll
  for (int off = 32; off; off >>= 1) dot += __shfl_down(dot, off);
  if ((tid & 63) == 0) red[tid >> 6] = dot;
  __syncthreads();
  if (tid == 0)
    delta[row] = __expf(red[0] + red[1] + red[2] + red[3] + dtb[0]);
}

// ---------------- chunked parallel scan ----------------
__global__ __launch_bounds__(256) void scan1_kernel(
    const unsigned short* __restrict__ U, const float* __restrict__ delta,
    const float* __restrict__ Adiag, float* __restrict__ Q, float* __restrict__ P)
{
  const int h = blockIdx.x * 1024 + threadIdx.x * 4;
  const int c = blockIdx.y, b = blockIdx.z;
  const float4 a = *(const float4*)(Adiag + h);
  const unsigned short* u = U + ((size_t)b * SEQ + c * CLEN) * H_DIM + h;
  const float* dl = delta + b * SEQ + c * CLEN;
  float4 st = {0.f, 0.f, 0.f, 0.f};
  float4 pr = {1.f, 1.f, 1.f, 1.f};
#pragma unroll 8
  for (int s = 0; s < CLEN; ++s) {
    const float d = dl[s];
    const ushort4 uv = *(const ushort4*)(u + (size_t)s * H_DIM);
    const float dx = __expf(d * a.x), dy = __expf(d * a.y);
    const float dz = __expf(d * a.z), dw = __expf(d * a.w);
    st.x = fmaf(st.x, dx, bf2f(uv.x)); st.y = fmaf(st.y, dy, bf2f(uv.y));
    st.z = fmaf(st.z, dz, bf2f(uv.z)); st.w = fmaf(st.w, dw, bf2f(uv.w));
    pr.x *= dx; pr.y *= dy; pr.z *= dz; pr.w *= dw;
  }
  const size_t idx = ((size_t)b * CCH + c) * H_DIM + h;
  *(float4*)(Q + idx) = st;
  *(float4*)(P + idx) = pr;
}

__global__ __launch_bounds__(256) void scan2_kernel(
    const float* __restrict__ Q, const float* __restrict__ P,
    const float* __restrict__ ctx, float* __restrict__ sIn,
    float* __restrict__ finalSt)
{
  const int h = blockIdx.x * 256 + threadIdx.x;
  const int b = blockIdx.y;
  float s = ctx[b * H_DIM + h];
#pragma unroll
  for (int c = 0; c < CCH; ++c) {
    const size_t idx = ((size_t)b * CCH + c) * H_DIM + h;
    sIn[idx] = s;
    s = fmaf(s, P[idx], Q[idx]);
  }
  finalSt[b * H_DIM + h] = s;
}

__global__ __launch_bounds__(256) void scan3_kernel(
    const unsigned short* __restrict__ U, const float* __restrict__ delta,
    const float* __restrict__ Adiag, const float* __restrict__ sIn,
    unsigned short* __restrict__ states)
{
  const int h = blockIdx.x * 1024 + threadIdx.x * 4;
  const int c = blockIdx.y, b = blockIdx.z;
  const float4 a = *(const float4*)(Adiag + h);
  const unsigned short* u = U + ((size_t)b * SEQ + c * CLEN) * H_DIM + h;
  unsigned short* so = states + ((size_t)b * SEQ + c * CLEN) * H_DIM + h;
  const float* dl = delta + b * SEQ + c * CLEN;
  float4 st = *(const float4*)(sIn + ((size_t)b * CCH + c) * H_DIM + h);
#pragma unroll 8
  for (int s = 0; s < CLEN; ++s) {
    const float d = dl[s];
    const ushort4 uv = *(const ushort4*)(u + (size_t)s * H_DIM);
    const float dx = __expf(d * a.x), dy = __expf(d * a.y);
    const float dz = __expf(d * a.z), dw = __expf(d * a.w);
    st.x = fmaf(st.x, dx, bf2f(uv.x)); st.y = fmaf(st.y, dy, bf2f(uv.y));
    st.z = fmaf(st.z, dz, bf2f(uv.z)); st.w = fmaf(st.w, dw, bf2f(uv.w));
    ushort4 ov = { f2bf(st.x), f2bf(st.y), f2bf(st.z), f2bf(st.w) };
    *(ushort4*)(so + (size_t)s * H_DIM) = ov;
  }
}

// ========== 256x256 8-phase bf16 GEMM, TEMPLATE-EXACT vmcnt placement =====
// Same-phase reads (barrier; lgkmcnt(0); MFMA), stages per template slots,
// vmcnt(6) ONLY at phases 4 and 8 (drains target >=3-phase-old loads).
// Hazards verified: WAR by issue order (each stage after its half's last
// read-phase barrier); RAW by drain coverage (P4 completes through P1's
// stage, P8 through P5's; every read sits after its stage's guarantee).
// XCD-grouped blocks, XOR-swizzled LDS, LDS-staged coalesced epilogue.
// EPI: 1 = bf16 out, 2 = GLU: out = Y * sigmoid(acc + gbias)  (f32 out)

#define BARR()  __builtin_amdgcn_s_barrier();
#define LGKM0() asm volatile("s_waitcnt lgkmcnt(0)");
#define VMC(N)  asm volatile("s_waitcnt vmcnt(" #N ")" ::: "memory");

#define RD_A(DST, PL, PHH, OFF) { _Pragma("unroll") for (int i_ = 0; i_ < 4; ++i_) { \
    DST[0][i_] = *(const s16x8*)((PL) + (OFF) + i_ * 4096); \
    DST[1][i_] = *(const s16x8*)((PHH) + (OFF) + i_ * 4096); } }
#define RD_B(DST, PL, PHH, OFF) { _Pragma("unroll") for (int j_ = 0; j_ < 2; ++j_) { \
    DST[0][j_] = *(const s16x8*)((PL) + (OFF) + j_ * 8192); \
    DST[1][j_] = *(const s16x8*)((PHH) + (OFF) + j_ * 8192); } }

#define QMM(IB, JB, AF, BF) { __builtin_amdgcn_s_setprio(1); \
  _Pragma("unroll") for (int i_ = 0; i_ < 4; ++i_) \
  _Pragma("unroll") for (int j_ = 0; j_ < 2; ++j_) { \
    acc[(IB)+i_][(JB)+j_] = __builtin_amdgcn_mfma_f32_16x16x32_bf16(AF[0][i_], BF[0][j_], acc[(IB)+i_][(JB)+j_], 0, 0, 0); \
    acc[(IB)+i_][(JB)+j_] = __builtin_amdgcn_mfma_f32_16x16x32_bf16(AF[1][i_], BF[1][j_], acc[(IB)+i_][(JB)+j_], 0, 0, 0); } \
  __builtin_amdgcn_s_setprio(0); }

#define STAGE_A(BUF, HH, TT) { const char* s_ = srcA + (HH) * 524288 + (TT) * 128; \
  char* d_ = ldsA + (BUF) * 32768 + (HH) * 16384 + tid16; \
  gl_lds16(s_, d_); gl_lds16(s_ + 262144, d_ + 8192); }
#define STAGE_B(BUF, HH, TT) { const char* s_ = srcB + (HH) * 524288 + (TT) * 128; \
  char* d_ = ldsB + (BUF) * 32768 + (HH) * 16384 + tid16; \
  gl_lds16(s_, d_); gl_lds16(s_ + 262144, d_ + 8192); }

template <int EPI>
__global__ __launch_bounds__(512, 2) void gemm8p(
    const char* __restrict__ Ab, const char* __restrict__ Bb,
    float* __restrict__ outF, unsigned short* __restrict__ outH,
    const unsigned short* __restrict__ Ybf, const float* __restrict__ gbias)
{
  extern __shared__ char lds[];
  char* ldsA = lds;            // 2 bufs x 32KB
  char* ldsB = lds + 65536;    // 2 bufs x 32KB

  const int tid  = threadIdx.x;
  const int lane = tid & 63, wid = tid >> 6;
  const int wr = wid >> 2, wc = wid & 3;       // 2x4 wave grid
  const int fr = lane & 15, kq = lane >> 4;

  // ---- XCD-grouped block swizzle: each XCD owns an 8(bm) x 4(bn) group ----
  const int bid = blockIdx.x;
  const int xcd = bid & 7;
  const int li  = bid >> 3;
  const int bm  = (xcd >> 1) * 8 + (li & 7);
  const int bn  = (xcd & 1) * 4 + (li >> 3);

  // ---- staging source (pre-swizzled global, linear LDS dest) ----
  const int grow = tid >> 3;
  const int gswz = ((tid & 7) ^ (grow & 7)) << 4;
  const char* srcA = Ab + ((size_t)(bm * 256 + grow)) * 4096 + gswz;
  const char* srcB = Bb + ((size_t)(bn * 256 + grow)) * 4096 + gswz;
  const int tid16 = tid << 4;

  // ---- swizzled ds_read base pointers ----
  const int sw0 = ((kq ^ (fr & 7)) << 4);
  const int sw1 = (((4 | kq) ^ (fr & 7)) << 4);
  const char* pa0b0 = ldsA + wr * 2048 + fr * 128 + sw0;
  const char* pa1b0 = ldsA + wr * 2048 + fr * 128 + sw1;
  const char* pa0b1 = pa0b0 + 32768;
  const char* pa1b1 = pa1b0 + 32768;
  const char* pb0b0 = ldsB + wc * 2048 + fr * 128 + sw0;
  const char* pb1b0 = ldsB + wc * 2048 + fr * 128 + sw1;
  const char* pb0b1 = pb0b0 + 32768;
  const char* pb1b1 = pb1b0 + 32768;

  f32x4 acc[8][4] = {};
  s16x8 a03[2][4], a47[2][4], b01[2][2], b23[2][2];

  // ---- prologue (template: vmcnt(4) after 4 halves, vmcnt(6) after +3) ----
  STAGE_A(0, 0, 0); STAGE_B(0, 0, 0); STAGE_B(0, 1, 0); STAGE_A(0, 1, 0);
  VMC(4);
  STAGE_A(1, 0, 1); STAGE_B(1, 0, 1); STAGE_B(1, 1, 1);
  VMC(6);
  BARR();

  // ---- main loop: 15 iters x 2 K-tiles (tiles 0..29) ----
  for (int t = 0; t < NKT / 2 - 1; ++t) {
    const int T0 = 2 * t;
    // P1: read A0h0+B0h0 frags; stage A1h1(T0+1)
    RD_A(a03, pa0b0, pa1b0, 0);
    RD_B(b01, pb0b0, pb1b0, 0);
    STAGE_A(1, 1, T0 + 1);
    BARR(); LGKM0(); QMM(0, 0, a03, b01); BARR();
    // P2: read B0h1; stage A0h0(T0+2)  [h0 free since P1]
    RD_B(b23, pb0b0, pb1b0, 16384);
    STAGE_A(0, 0, T0 + 2);
    BARR(); LGKM0(); QMM(0, 2, a03, b23); BARR();
    // P3: read A0h1; stage B0h0(T0+2)
    RD_A(a47, pa0b0, pa1b0, 16384);
    STAGE_B(0, 0, T0 + 2);
    BARR(); LGKM0(); QMM(4, 0, a47, b01); BARR();
    // P4: regs only; stage B0h1(T0+2); counted vmcnt
    STAGE_B(0, 1, T0 + 2);
    BARR(); QMM(4, 2, a47, b23); VMC(6); BARR();
    // P5: read A1h0+B1h0; stage A0h1(T0+2)
    RD_A(a03, pa0b1, pa1b1, 0);
    RD_B(b01, pb0b1, pb1b1, 0);
    STAGE_A(0, 1, T0 + 2);
    BARR(); LGKM0(); QMM(0, 0, a03, b01); BARR();
    // P6: read B1h1; stage A1h0(T0+3)
    RD_B(b23, pb0b1, pb1b1, 16384);
    STAGE_A(1, 0, T0 + 3);
    BARR(); LGKM0(); QMM(0, 2, a03, b23); BARR();
    // P7: read A1h1; stage B1h0(T0+3)
    RD_A(a47, pa0b1, pa1b1, 16384);
    STAGE_B(1, 0, T0 + 3);
    BARR(); LGKM0(); QMM(4, 0, a47, b01); BARR();
    // P8: regs only; stage B1h1(T0+3); counted vmcnt
    STAGE_B(1, 1, T0 + 3);
    BARR(); QMM(4, 2, a47, b23); VMC(6); BARR();
  }

  // ---- epilogue: tiles 30 (buf0) and 31 (buf1) ----
  RD_A(a03, pa0b0, pa1b0, 0);
  RD_B(b01, pb0b0, pb1b0, 0);
  STAGE_A(1, 1, 31);
  BARR(); LGKM0(); QMM(0, 0, a03, b01); BARR();
  RD_B(b23, pb0b0, pb1b0, 16384);
  BARR(); LGKM0(); QMM(0, 2, a03, b23); BARR();
  RD_A(a47, pa0b0, pa1b0, 16384);
  BARR(); LGKM0(); QMM(4, 0, a47, b01); BARR();
  BARR(); QMM(4, 2, a47, b23); VMC(0); BARR();
  RD_A(a03, pa0b1, pa1b1, 0);
  RD_B(b01, pb0b1, pb1b1, 0);
  QMM(0, 0, a03, b01);
  RD_B(b23, pb0b1, pb1b1, 16384);
  QMM(0, 2, a03, b23);
  RD_A(a47, pa0b1, pa1b1, 16384);
  QMM(4, 0, a47, b01);
  QMM(4, 2, a47, b23);

  // ---- LDS-staged coalesced C write ----
  __syncthreads();
  const int cr = (lane >> 4) << 2;
  const int cc = lane & 15;
  if constexpr (EPI == 1) {
#pragma unroll
    for (int i = 0; i < 8; ++i)
#pragma unroll
      for (int j = 0; j < 4; ++j)
#pragma unroll
        for (int r = 0; r < 4; ++r) {
          const int row = (2 * i + wr) * 16 + cr + r;
          const int col = (4 * j + wc) * 16 + cc;
          const int off = (row * 512 + col * 2) ^ ((row & 7) << 4);
          *(unsigned short*)(lds + off) = f2bf(acc[i][j][r]);
        }
    __syncthreads();
#pragma unroll
    for (int it = 0; it < 16; ++it) {
      const int L = it * 8192 + tid * 16;
      const int row = L >> 9, inrow = L & 511;
      const s16x8 v = *(const s16x8*)(lds + (L ^ ((row & 7) << 4)));
      *(s16x8*)(outH + ((size_t)(bm * 256 + row)) * H_DIM + bn * 256 + (inrow >> 1)) = v;
    }
  } else {
#pragma unroll
    for (int p = 0; p < 2; ++p) {
      if (p) __syncthreads();
#pragma unroll
      for (int i = 4 * p; i < 4 * p + 4; ++i)
#pragma unroll
        for (int j = 0; j < 4; ++j)
#pragma unroll
          for (int r = 0; r < 4; ++r) {
            const int lrow = (2 * i + wr) * 16 + cr + r - 128 * p;
            const int col = (4 * j + wc) * 16 + cc;
            const int off = (lrow * 1024 + col * 4) ^ ((lrow & 7) << 4);
            *(float*)(lds + off) = acc[i][j][r];
          }
      __syncthreads();
#pragma unroll
      for (int it = 0; it < 16; ++it) {
        const int L = it * 8192 + tid * 16;
        const int lrow = L >> 10, inrow = L & 1023;
        const f32x4 v = *(const f32x4*)(lds + (L ^ ((lrow & 7) << 4)));
        const size_t growg = (size_t)(bm * 256 + 128 * p + lrow);
        const int gcol = bn * 256 + (inrow >> 2);
        const float4 gb4 = *(const float4*)(gbias + gcol);
        const ushort4 y4 = *(const ushort4*)(Ybf + growg * H_DIM + gcol);
        float4 o;
        o.x = bf2f(y4.x) / (1.f + __expf(-(v[0] + gb4.x)));
        o.y = bf2f(y4.y) / (1.f + __expf(-(v[1] + gb4.y)));
        o.z = bf2f(y4.z) / (1.f + __expf(-(v[2] + gb4.z)));
        o.w = bf2f(y4.w) / (1.f + __expf(-(v[3] + gb4.w)));
        *(float4*)(outF + growg * H_DIM + gcol) = o;
      }
    }
  }
}

extern "C" void kernel_launch(void* const* d_in, const int* in_sizes, int n_in,
                              void* d_out, int out_size, void* d_ws, size_t ws_size,
                              hipStream_t stream) {
  (void)in_sizes; (void)n_in; (void)out_size; (void)ws_size;
  const float* x     = (const float*)d_in[0];
  const float* ctx   = (const float*)d_in[1];
  const float* Adiag = (const float*)d_in[2];
  const float* Bm    = (const float*)d_in[3];
  const float* Cm    = (const float*)d_in[4];
  const float* dtk   = (const float*)d_in[5];
  const float* dtb   = (const float*)d_in[6];
  const float* gk    = (const float*)d_in[7];
  const float* gb    = (const float*)d_in[8];
  const float* lns   = (const float*)d_in[9];
  const float* lnb   = (const float*)d_in[10];
  float* outF = (float*)d_out;

  char* ws = (char*)d_ws;
  unsigned short* xnY    = (unsigned short*)ws; ws += (size_t)M_DIM * H_DIM * 2;  // xn, later Y
  unsigned short* U      = (unsigned short*)ws; ws += (size_t)M_DIM * H_DIM * 2;
  unsigned short* states = (unsigned short*)ws; ws += (size_t)M_DIM * H_DIM * 2;
  unsigned short* T1     = (unsigned short*)ws; ws += (size_t)H_DIM * H_DIM * 2;
  unsigned short* T2     = (unsigned short*)ws; ws += (size_t)H_DIM * H_DIM * 2;
  unsigned short* T3     = (unsigned short*)ws; ws += (size_t)H_DIM * H_DIM * 2;
  float* delta           = (float*)ws;          ws += (size_t)M_DIM * 4;
  float* Qbuf            = (float*)ws;          ws += (size_t)B_SZ * CCH * H_DIM * 4;
  float* Pbuf            = (float*)ws;          ws += (size_t)B_SZ * CCH * H_DIM * 4;
  float* sInBuf          = (float*)ws;          ws += (size_t)B_SZ * CCH * H_DIM * 4;

  hipFuncSetAttribute((const void*)&gemm8p<1>,
                      hipFuncAttributeMaxDynamicSharedMemorySize, 131072);
  hipFuncSetAttribute((const void*)&gemm8p<2>,
                      hipFuncAttributeMaxDynamicSharedMemorySize, 131072);

  dim3 tb(256);
  transpose3_kernel<<<dim3(64, 64, 3), tb, 0, stream>>>(Bm, T1, Cm, T2, gk, T3);
  ln_delta_kernel<<<M_DIM, tb, 0, stream>>>(x, lns, lnb, dtk, dtb, xnY, delta);
  gemm8p<1><<<256, 512, 131072, stream>>>(
      (const char*)xnY, (const char*)T1, nullptr, U, nullptr, nullptr);
  scan1_kernel<<<dim3(H_DIM / 1024, CCH, B_SZ), tb, 0, stream>>>(
      U, delta, Adiag, Qbuf, Pbuf);
  scan2_kernel<<<dim3(H_DIM / 256, B_SZ), tb, 0, stream>>>(
      Qbuf, Pbuf, ctx, sInBuf, outF + (size_t)M_DIM * H_DIM);
  scan3_kernel<<<dim3(H_DIM / 1024, CCH, B_SZ), tb, 0, stream>>>(
      U, delta, Adiag, sInBuf, states);
  gemm8p<1><<<256, 512, 131072, stream>>>(
      (const char*)states, (const char*)T2, nullptr, xnY, nullptr, nullptr);
  gemm8p<2><<<256, 512, 131072, stream>>>(
      (const char*)xnY, (const char*)T3, outF, nullptr, xnY, gb);
}

// Round 11
// 250.667 us; speedup vs baseline: 1.1092x; 1.0074x over previous
//
#include <hip/hip_runtime.h>
#include <hip/hip_bf16.h>

#define H_DIM 2048
#define B_SZ  8
#define SEQ   1024
#define M_DIM (B_SZ*SEQ)   // 8192
#define KDIM  2048
#define NKT   (KDIM/64)    // 32 K-tiles
#define CCH   32           // scan chunks
#define CLEN  (SEQ/CCH)    // 32 steps per chunk

using f32x4 = __attribute__((ext_vector_type(4))) float;
using s16x8 = __attribute__((ext_vector_type(8))) short;

__device__ __forceinline__ float bf2f(unsigned short u) {
  unsigned int x = ((unsigned int)u) << 16;
  return __builtin_bit_cast(float, x);
}
__device__ __forceinline__ unsigned short f2bf(float f) {
  unsigned int x = __builtin_bit_cast(unsigned int, f);
  unsigned int r = (x + 0x7fffu + ((x >> 16) & 1u)) >> 16;
  return (unsigned short)r;
}

__device__ __forceinline__ void gl_lds16(const void* g, void* l) {
  __builtin_amdgcn_global_load_lds(
      (__attribute__((address_space(1))) void*)g,
      (__attribute__((address_space(3))) void*)l, 16, 0, 0);
}

// ====== fused pre-pass: 3x weight transpose (fp32->bf16^T) + LN+clip+delta ==
// blocks [0, 12288): transpose (4096 blocks per matrix); [12288, 20480): LN rows
__global__ __launch_bounds__(256) void pre_kernel(
    const float* __restrict__ s0, unsigned short* __restrict__ d0,
    const float* __restrict__ s1, unsigned short* __restrict__ d1,
    const float* __restrict__ s2, unsigned short* __restrict__ d2,
    const float* __restrict__ x, const float* __restrict__ lns,
    const float* __restrict__ lnb, const float* __restrict__ dtk,
    const float* __restrict__ dtb, unsigned short* __restrict__ xn,
    float* __restrict__ delta)
{
  __shared__ float t[32][33];
  __shared__ float red[8];
  const int bid = blockIdx.x;
  const int tid = threadIdx.x;

  if (bid < 12288) {
    // ---------------- transpose part ----------------
    const int z = bid >> 12;              // /4096
    const int r = bid & 4095;
    const int c0 = (r & 63) << 5, r0 = (r >> 6) << 5;
    const float* src = (z == 0) ? s0 : (z == 1) ? s1 : s2;
    unsigned short* dst = (z == 0) ? d0 : (z == 1) ? d1 : d2;
    const int tx = tid & 31, ty = tid >> 5;
#pragma unroll
    for (int i = 0; i < 32; i += 8)
      t[ty + i][tx] = src[(size_t)(r0 + ty + i) * H_DIM + (c0 + tx)];
    __syncthreads();
#pragma unroll
    for (int i = 0; i < 32; i += 8)
      dst[(size_t)(c0 + ty + i) * H_DIM + (r0 + tx)] = f2bf(t[tx][ty + i]);
    return;
  }

  // ---------------- LayerNorm + clip + delta part ----------------
  const int row = bid - 12288;
  const float* xr = x + (size_t)row * H_DIM;
  float v[8];
  *(float4*)&v[0] = ((const float4*)xr)[tid * 2];
  *(float4*)&v[4] = ((const float4*)xr)[tid * 2 + 1];
  float sm1 = 0.f, sm2 = 0.f;
#pragma unroll
  for (int j = 0; j < 8; ++j) { sm1 += v[j]; sm2 += v[j] * v[j]; }
#pragma unroll
  for (int off = 32; off; off >>= 1) {
    sm1 += __shfl_down(sm1, off);
    sm2 += __shfl_down(sm2, off);
  }
  if ((tid & 63) == 0) { red[tid >> 6] = sm1; red[4 + (tid >> 6)] = sm2; }
  __syncthreads();
  float mean = (red[0] + red[1] + red[2] + red[3]) * (1.0f / H_DIM);
  float var  = (red[4] + red[5] + red[6] + red[7]) * (1.0f / H_DIM) - mean * mean;
  float rstd = rsqrtf(var + 1e-6f);

  float sc[8], bi[8], dk[8];
  *(float4*)&sc[0] = ((const float4*)lns)[tid * 2];
  *(float4*)&sc[4] = ((const float4*)lns)[tid * 2 + 1];
  *(float4*)&bi[0] = ((const float4*)lnb)[tid * 2];
  *(float4*)&bi[4] = ((const float4*)lnb)[tid * 2 + 1];
  *(float4*)&dk[0] = ((const float4*)dtk)[tid * 2];
  *(float4*)&dk[4] = ((const float4*)dtk)[tid * 2 + 1];

  float dot = 0.f;
  s16x8 o;
#pragma unroll
  for (int j = 0; j < 8; ++j) {
    float xv = (v[j] - mean) * rstd * sc[j] + bi[j];
    xv = fminf(fmaxf(xv, -1.0e6f), 1.0e6f);
    dot += xv * dk[j];
    o[j] = (short)f2bf(xv);
  }
  *(s16x8*)(xn + (size_t)row * H_DIM + tid * 8) = o;

  __syncthreads();
#pragma unroll
  for (int off = 32; off; off >>= 1) dot += __shfl_down(dot, off);
  if ((tid & 63) == 0) red[tid >> 6] = dot;
  __syncthreads();
  if (tid == 0)
    delta[row] = __expf(red[0] + red[1] + red[2] + red[3] + dtb[0]);
}

// ---------------- chunked parallel scan ----------------
// scan1: per (b, chunk, h4): local scan (zero init) -> Q, decay product -> P
__global__ __launch_bounds__(256) void scan1_kernel(
    const unsigned short* __restrict__ U, const float* __restrict__ delta,
    const float* __restrict__ Adiag, float* __restrict__ Q, float* __restrict__ P)
{
  const int h = blockIdx.x * 1024 + threadIdx.x * 4;
  const int c = blockIdx.y, b = blockIdx.z;
  const float4 a = *(const float4*)(Adiag + h);
  const unsigned short* u = U + ((size_t)b * SEQ + c * CLEN) * H_DIM + h;
  const float* dl = delta + b * SEQ + c * CLEN;
  float4 st = {0.f, 0.f, 0.f, 0.f};
  float4 pr = {1.f, 1.f, 1.f, 1.f};
#pragma unroll 8
  for (int s = 0; s < CLEN; ++s) {
    const float d = dl[s];
    const ushort4 uv = *(const ushort4*)(u + (size_t)s * H_DIM);
    const float dx = __expf(d * a.x), dy = __expf(d * a.y);
    const float dz = __expf(d * a.z), dw = __expf(d * a.w);
    st.x = fmaf(st.x, dx, bf2f(uv.x)); st.y = fmaf(st.y, dy, bf2f(uv.y));
    st.z = fmaf(st.z, dz, bf2f(uv.z)); st.w = fmaf(st.w, dw, bf2f(uv.w));
    pr.x *= dx; pr.y *= dy; pr.z *= dz; pr.w *= dw;
  }
  const size_t idx = ((size_t)b * CCH + c) * H_DIM + h;
  *(float4*)(Q + idx) = st;
  *(float4*)(P + idx) = pr;
}

// scan3: recompute chunk-prefix from Q/P (identical fma sequence to old
// scan2 -> bitwise-same seeds), then replay chunk from U; c==31 also emits
// the final state from the replay (per-step path, matches reference).
__global__ __launch_bounds__(256) void scan3_kernel(
    const unsigned short* __restrict__ U, const float* __restrict__ delta,
    const float* __restrict__ Adiag, const float* __restrict__ Q,
    const float* __restrict__ P, const float* __restrict__ ctx,
    unsigned short* __restrict__ states, float* __restrict__ finalSt)
{
  const int h = blockIdx.x * 1024 + threadIdx.x * 4;
  const int c = blockIdx.y, b = blockIdx.z;
  const float4 a = *(const float4*)(Adiag + h);

  float4 st = *(const float4*)(ctx + (size_t)b * H_DIM + h);
  for (int cc = 0; cc < c; ++cc) {
    const size_t idx = ((size_t)b * CCH + cc) * H_DIM + h;
    const float4 P4 = *(const float4*)(P + idx);
    const float4 Q4 = *(const float4*)(Q + idx);
    st.x = fmaf(st.x, P4.x, Q4.x); st.y = fmaf(st.y, P4.y, Q4.y);
    st.z = fmaf(st.z, P4.z, Q4.z); st.w = fmaf(st.w, P4.w, Q4.w);
  }

  const unsigned short* u = U + ((size_t)b * SEQ + c * CLEN) * H_DIM + h;
  unsigned short* so = states + ((size_t)b * SEQ + c * CLEN) * H_DIM + h;
  const float* dl = delta + b * SEQ + c * CLEN;
#pragma unroll 8
  for (int s = 0; s < CLEN; ++s) {
    const float d = dl[s];
    const ushort4 uv = *(const ushort4*)(u + (size_t)s * H_DIM);
    const float dx = __expf(d * a.x), dy = __expf(d * a.y);
    const float dz = __expf(d * a.z), dw = __expf(d * a.w);
    st.x = fmaf(st.x, dx, bf2f(uv.x)); st.y = fmaf(st.y, dy, bf2f(uv.y));
    st.z = fmaf(st.z, dz, bf2f(uv.z)); st.w = fmaf(st.w, dw, bf2f(uv.w));
    ushort4 ov = { f2bf(st.x), f2bf(st.y), f2bf(st.z), f2bf(st.w) };
    *(ushort4*)(so + (size_t)s * H_DIM) = ov;
  }
  if (c == CCH - 1)
    *(float4*)(finalSt + (size_t)b * H_DIM + h) = st;
}

// ========== 256x256 8-phase bf16 GEMM (round-10, best total) =====
// Same-phase reads (barrier; lgkmcnt(0); MFMA), vmcnt(6) only at P4/P8.
// XCD-grouped blocks, XOR-swizzled LDS, LDS-staged coalesced epilogue.
// EPI: 1 = bf16 out, 2 = GLU: out = Y * sigmoid(acc + gbias)  (f32 out)

#define BARR()  __builtin_amdgcn_s_barrier();
#define LGKM0() asm volatile("s_waitcnt lgkmcnt(0)");
#define VMC(N)  asm volatile("s_waitcnt vmcnt(" #N ")" ::: "memory");

#define RD_A(DST, PL, PHH, OFF) { _Pragma("unroll") for (int i_ = 0; i_ < 4; ++i_) { \
    DST[0][i_] = *(const s16x8*)((PL) + (OFF) + i_ * 4096); \
    DST[1][i_] = *(const s16x8*)((PHH) + (OFF) + i_ * 4096); } }
#define RD_B(DST, PL, PHH, OFF) { _Pragma("unroll") for (int j_ = 0; j_ < 2; ++j_) { \
    DST[0][j_] = *(const s16x8*)((PL) + (OFF) + j_ * 8192); \
    DST[1][j_] = *(const s16x8*)((PHH) + (OFF) + j_ * 8192); } }

#define QMM(IB, JB, AF, BF) { __builtin_amdgcn_s_setprio(1); \
  _Pragma("unroll") for (int i_ = 0; i_ < 4; ++i_) \
  _Pragma("unroll") for (int j_ = 0; j_ < 2; ++j_) { \
    acc[(IB)+i_][(JB)+j_] = __builtin_amdgcn_mfma_f32_16x16x32_bf16(AF[0][i_], BF[0][j_], acc[(IB)+i_][(JB)+j_], 0, 0, 0); \
    acc[(IB)+i_][(JB)+j_] = __builtin_amdgcn_mfma_f32_16x16x32_bf16(AF[1][i_], BF[1][j_], acc[(IB)+i_][(JB)+j_], 0, 0, 0); } \
  __builtin_amdgcn_s_setprio(0); }

#define STAGE_A(BUF, HH, TT) { const char* s_ = srcA + (HH) * 524288 + (TT) * 128; \
  char* d_ = ldsA + (BUF) * 32768 + (HH) * 16384 + tid16; \
  gl_lds16(s_, d_); gl_lds16(s_ + 262144, d_ + 8192); }
#define STAGE_B(BUF, HH, TT) { const char* s_ = srcB + (HH) * 524288 + (TT) * 128; \
  char* d_ = ldsB + (BUF) * 32768 + (HH) * 16384 + tid16; \
  gl_lds16(s_, d_); gl_lds16(s_ + 262144, d_ + 8192); }

template <int EPI>
__global__ __launch_bounds__(512, 2) void gemm8p(
    const char* __restrict__ Ab, const char* __restrict__ Bb,
    float* __restrict__ outF, unsigned short* __restrict__ outH,
    const unsigned short* __restrict__ Ybf, const float* __restrict__ gbias)
{
  extern __shared__ char lds[];
  char* ldsA = lds;            // 2 bufs x 32KB
  char* ldsB = lds + 65536;    // 2 bufs x 32KB

  const int tid  = threadIdx.x;
  const int lane = tid & 63, wid = tid >> 6;
  const int wr = wid >> 2, wc = wid & 3;       // 2x4 wave grid
  const int fr = lane & 15, kq = lane >> 4;

  // ---- XCD-grouped block swizzle: each XCD owns an 8(bm) x 4(bn) group ----
  const int bid = blockIdx.x;
  const int xcd = bid & 7;
  const int li  = bid >> 3;
  const int bm  = (xcd >> 1) * 8 + (li & 7);
  const int bn  = (xcd & 1) * 4 + (li >> 3);

  // ---- staging source (pre-swizzled global, linear LDS dest) ----
  const int grow = tid >> 3;
  const int gswz = ((tid & 7) ^ (grow & 7)) << 4;
  const char* srcA = Ab + ((size_t)(bm * 256 + grow)) * 4096 + gswz;
  const char* srcB = Bb + ((size_t)(bn * 256 + grow)) * 4096 + gswz;
  const int tid16 = tid << 4;

  // ---- swizzled ds_read base pointers ----
  const int sw0 = ((kq ^ (fr & 7)) << 4);
  const int sw1 = (((4 | kq) ^ (fr & 7)) << 4);
  const char* pa0b0 = ldsA + wr * 2048 + fr * 128 + sw0;
  const char* pa1b0 = ldsA + wr * 2048 + fr * 128 + sw1;
  const char* pa0b1 = pa0b0 + 32768;
  const char* pa1b1 = pa1b0 + 32768;
  const char* pb0b0 = ldsB + wc * 2048 + fr * 128 + sw0;
  const char* pb1b0 = ldsB + wc * 2048 + fr * 128 + sw1;
  const char* pb0b1 = pb0b0 + 32768;
  const char* pb1b1 = pb1b0 + 32768;

  f32x4 acc[8][4] = {};
  s16x8 a03[2][4], a47[2][4], b01[2][2], b23[2][2];

  // ---- prologue (vmcnt(4) after 4 halves, vmcnt(6) after +3) ----
  STAGE_A(0, 0, 0); STAGE_B(0, 0, 0); STAGE_B(0, 1, 0); STAGE_A(0, 1, 0);
  VMC(4);
  STAGE_A(1, 0, 1); STAGE_B(1, 0, 1); STAGE_B(1, 1, 1);
  VMC(6);
  BARR();

  // ---- main loop: 15 iters x 2 K-tiles (tiles 0..29) ----
  for (int t = 0; t < NKT / 2 - 1; ++t) {
    const int T0 = 2 * t;
    RD_A(a03, pa0b0, pa1b0, 0);
    RD_B(b01, pb0b0, pb1b0, 0);
    STAGE_A(1, 1, T0 + 1);
    BARR(); LGKM0(); QMM(0, 0, a03, b01); BARR();
    RD_B(b23, pb0b0, pb1b0, 16384);
    STAGE_A(0, 0, T0 + 2);
    BARR(); LGKM0(); QMM(0, 2, a03, b23); BARR();
    RD_A(a47, pa0b0, pa1b0, 16384);
    STAGE_B(0, 0, T0 + 2);
    BARR(); LGKM0(); QMM(4, 0, a47, b01); BARR();
    STAGE_B(0, 1, T0 + 2);
    BARR(); QMM(4, 2, a47, b23); VMC(6); BARR();
    RD_A(a03, pa0b1, pa1b1, 0);
    RD_B(b01, pb0b1, pb1b1, 0);
    STAGE_A(0, 1, T0 + 2);
    BARR(); LGKM0(); QMM(0, 0, a03, b01); BARR();
    RD_B(b23, pb0b1, pb1b1, 16384);
    STAGE_A(1, 0, T0 + 3);
    BARR(); LGKM0(); QMM(0, 2, a03, b23); BARR();
    RD_A(a47, pa0b1, pa1b1, 16384);
    STAGE_B(1, 0, T0 + 3);
    BARR(); LGKM0(); QMM(4, 0, a47, b01); BARR();
    STAGE_B(1, 1, T0 + 3);
    BARR(); QMM(4, 2, a47, b23); VMC(6); BARR();
  }

  // ---- epilogue: tiles 30 (buf0) and 31 (buf1) ----
  RD_A(a03, pa0b0, pa1b0, 0);
  RD_B(b01, pb0b0, pb1b0, 0);
  STAGE_A(1, 1, 31);
  BARR(); LGKM0(); QMM(0, 0, a03, b01); BARR();
  RD_B(b23, pb0b0, pb1b0, 16384);
  BARR(); LGKM0(); QMM(0, 2, a03, b23); BARR();
  RD_A(a47, pa0b0, pa1b0, 16384);
  BARR(); LGKM0(); QMM(4, 0, a47, b01); BARR();
  BARR(); QMM(4, 2, a47, b23); VMC(0); BARR();
  RD_A(a03, pa0b1, pa1b1, 0);
  RD_B(b01, pb0b1, pb1b1, 0);
  QMM(0, 0, a03, b01);
  RD_B(b23, pb0b1, pb1b1, 16384);
  QMM(0, 2, a03, b23);
  RD_A(a47, pa0b1, pa1b1, 16384);
  QMM(4, 0, a47, b01);
  QMM(4, 2, a47, b23);

  // ---- LDS-staged coalesced C write ----
  __syncthreads();
  const int cr = (lane >> 4) << 2;
  const int cc = lane & 15;
  if constexpr (EPI == 1) {
#pragma unroll
    for (int i = 0; i < 8; ++i)
#pragma unroll
      for (int j = 0; j < 4; ++j)
#pragma unroll
        for (int r = 0; r < 4; ++r) {
          const int row = (2 * i + wr) * 16 + cr + r;
          const int col = (4 * j + wc) * 16 + cc;
          const int off = (row * 512 + col * 2) ^ ((row & 7) << 4);
          *(unsigned short*)(lds + off) = f2bf(acc[i][j][r]);
        }
    __syncthreads();
#pragma unroll
    for (int it = 0; it < 16; ++it) {
      const int L = it * 8192 + tid * 16;
      const int row = L >> 9, inrow = L & 511;
      const s16x8 v = *(const s16x8*)(lds + (L ^ ((row & 7) << 4)));
      *(s16x8*)(outH + ((size_t)(bm * 256 + row)) * H_DIM + bn * 256 + (inrow >> 1)) = v;
    }
  } else {
#pragma unroll
    for (int p = 0; p < 2; ++p) {
      if (p) __syncthreads();
#pragma unroll
      for (int i = 4 * p; i < 4 * p + 4; ++i)
#pragma unroll
        for (int j = 0; j < 4; ++j)
#pragma unroll
          for (int r = 0; r < 4; ++r) {
            const int lrow = (2 * i + wr) * 16 + cr + r - 128 * p;
            const int col = (4 * j + wc) * 16 + cc;
            const int off = (lrow * 1024 + col * 4) ^ ((lrow & 7) << 4);
            *(float*)(lds + off) = acc[i][j][r];
          }
      __syncthreads();
#pragma unroll
      for (int it = 0; it < 16; ++it) {
        const int L = it * 8192 + tid * 16;
        const int lrow = L >> 10, inrow = L & 1023;
        const f32x4 v = *(const f32x4*)(lds + (L ^ ((lrow & 7) << 4)));
        const size_t growg = (size_t)(bm * 256 + 128 * p + lrow);
        const int gcol = bn * 256 + (inrow >> 2);
        const float4 gb4 = *(const float4*)(gbias + gcol);
        const ushort4 y4 = *(const ushort4*)(Ybf + growg * H_DIM + gcol);
        float4 o;
        o.x = bf2f(y4.x) / (1.f + __expf(-(v[0] + gb4.x)));
        o.y = bf2f(y4.y) / (1.f + __expf(-(v[1] + gb4.y)));
        o.z = bf2f(y4.z) / (1.f + __expf(-(v[2] + gb4.z)));
        o.w = bf2f(y4.w) / (1.f + __expf(-(v[3] + gb4.w)));
        *(float4*)(outF + growg * H_DIM + gcol) = o;
      }
    }
  }
}

extern "C" void kernel_launch(void* const* d_in, const int* in_sizes, int n_in,
                              void* d_out, int out_size, void* d_ws, size_t ws_size,
                              hipStream_t stream) {
  (void)in_sizes; (void)n_in; (void)out_size; (void)ws_size;
  const float* x     = (const float*)d_in[0];
  const float* ctx   = (const float*)d_in[1];
  const float* Adiag = (const float*)d_in[2];
  const float* Bm    = (const float*)d_in[3];
  const float* Cm    = (const float*)d_in[4];
  const float* dtk   = (const float*)d_in[5];
  const float* dtb   = (const float*)d_in[6];
  const float* gk    = (const float*)d_in[7];
  const float* gb    = (const float*)d_in[8];
  const float* lns   = (const float*)d_in[9];
  const float* lnb   = (const float*)d_in[10];
  float* outF = (float*)d_out;

  char* ws = (char*)d_ws;
  unsigned short* xnY    = (unsigned short*)ws; ws += (size_t)M_DIM * H_DIM * 2;  // xn, later Y
  unsigned short* U      = (unsigned short*)ws; ws += (size_t)M_DIM * H_DIM * 2;
  unsigned short* states = (unsigned short*)ws; ws += (size_t)M_DIM * H_DIM * 2;
  unsigned short* T1     = (unsigned short*)ws; ws += (size_t)H_DIM * H_DIM * 2;
  unsigned short* T2     = (unsigned short*)ws; ws += (size_t)H_DIM * H_DIM * 2;
  unsigned short* T3     = (unsigned short*)ws; ws += (size_t)H_DIM * H_DIM * 2;
  float* delta           = (float*)ws;          ws += (size_t)M_DIM * 4;
  float* Qbuf            = (float*)ws;          ws += (size_t)B_SZ * CCH * H_DIM * 4;
  float* Pbuf            = (float*)ws;          ws += (size_t)B_SZ * CCH * H_DIM * 4;

  hipFuncSetAttribute((const void*)&gemm8p<1>,
                      hipFuncAttributeMaxDynamicSharedMemorySize, 131072);
  hipFuncSetAttribute((const void*)&gemm8p<2>,
                      hipFuncAttributeMaxDynamicSharedMemorySize, 131072);

  dim3 tb(256);
  pre_kernel<<<12288 + M_DIM, tb, 0, stream>>>(
      Bm, T1, Cm, T2, gk, T3, x, lns, lnb, dtk, dtb, xnY, delta);
  gemm8p<1><<<256, 512, 131072, stream>>>(
      (const char*)xnY, (const char*)T1, nullptr, U, nullptr, nullptr);
  scan1_kernel<<<dim3(H_DIM / 1024, CCH, B_SZ), tb, 0, stream>>>(
      U, delta, Adiag, Qbuf, Pbuf);
  scan3_kernel<<<dim3(H_DIM / 1024, CCH, B_SZ), tb, 0, stream>>>(
      U, delta, Adiag, Qbuf, Pbuf, ctx, states, outF + (size_t)M_DIM * H_DIM);
  gemm8p<1><<<256, 512, 131072, stream>>>(
      (const char*)states, (const char*)T2, nullptr, xnY, nullptr, nullptr);
  gemm8p<2><<<256, 512, 131072, stream>>>(
      (const char*)xnY, (const char*)T3, outF, nullptr, xnY, gb);
}

// Round 12
// 247.056 us; speedup vs baseline: 1.1254x; 1.0146x over previous
//
#include <hip/hip_runtime.h>
#include <hip/hip_bf16.h>

#define H_DIM 2048
#define B_SZ  8
#define SEQ   1024
#define M_DIM (B_SZ*SEQ)   // 8192
#define KDIM  2048
#define NKT   (KDIM/64)    // 32 K-tiles
#define CCH   32           // scan chunks
#define CLEN  (SEQ/CCH)    // 32 steps per chunk

using f32x4 = __attribute__((ext_vector_type(4))) float;
using s16x8 = __attribute__((ext_vector_type(8))) short;

__device__ __forceinline__ float bf2f(unsigned short u) {
  unsigned int x = ((unsigned int)u) << 16;
  return __builtin_bit_cast(float, x);
}
__device__ __forceinline__ unsigned short f2bf(float f) {
  unsigned int x = __builtin_bit_cast(unsigned int, f);
  unsigned int r = (x + 0x7fffu + ((x >> 16) & 1u)) >> 16;
  return (unsigned short)r;
}

__device__ __forceinline__ void gl_lds16(const void* g, void* l) {
  __builtin_amdgcn_global_load_lds(
      (__attribute__((address_space(1))) void*)g,
      (__attribute__((address_space(3))) void*)l, 16, 0, 0);
}

// ====== fused pre-pass: 3x weight transpose (fp32->bf16^T) + LN+clip+delta ==
// blocks [0, 12288): transpose (4096 blocks per matrix); [12288, 20480): LN rows
__global__ __launch_bounds__(256) void pre_kernel(
    const float* __restrict__ s0, unsigned short* __restrict__ d0,
    const float* __restrict__ s1, unsigned short* __restrict__ d1,
    const float* __restrict__ s2, unsigned short* __restrict__ d2,
    const float* __restrict__ x, const float* __restrict__ lns,
    const float* __restrict__ lnb, const float* __restrict__ dtk,
    const float* __restrict__ dtb, unsigned short* __restrict__ xn,
    float* __restrict__ delta)
{
  __shared__ float t[32][33];
  __shared__ float red[8];
  const int bid = blockIdx.x;
  const int tid = threadIdx.x;

  if (bid < 12288) {
    const int z = bid >> 12;
    const int r = bid & 4095;
    const int c0 = (r & 63) << 5, r0 = (r >> 6) << 5;
    const float* src = (z == 0) ? s0 : (z == 1) ? s1 : s2;
    unsigned short* dst = (z == 0) ? d0 : (z == 1) ? d1 : d2;
    const int tx = tid & 31, ty = tid >> 5;
#pragma unroll
    for (int i = 0; i < 32; i += 8)
      t[ty + i][tx] = src[(size_t)(r0 + ty + i) * H_DIM + (c0 + tx)];
    __syncthreads();
#pragma unroll
    for (int i = 0; i < 32; i += 8)
      dst[(size_t)(c0 + ty + i) * H_DIM + (r0 + tx)] = f2bf(t[tx][ty + i]);
    return;
  }

  const int row = bid - 12288;
  const float* xr = x + (size_t)row * H_DIM;
  float v[8];
  *(float4*)&v[0] = ((const float4*)xr)[tid * 2];
  *(float4*)&v[4] = ((const float4*)xr)[tid * 2 + 1];
  float sm1 = 0.f, sm2 = 0.f;
#pragma unroll
  for (int j = 0; j < 8; ++j) { sm1 += v[j]; sm2 += v[j] * v[j]; }
#pragma unroll
  for (int off = 32; off; off >>= 1) {
    sm1 += __shfl_down(sm1, off);
    sm2 += __shfl_down(sm2, off);
  }
  if ((tid & 63) == 0) { red[tid >> 6] = sm1; red[4 + (tid >> 6)] = sm2; }
  __syncthreads();
  float mean = (red[0] + red[1] + red[2] + red[3]) * (1.0f / H_DIM);
  float var  = (red[4] + red[5] + red[6] + red[7]) * (1.0f / H_DIM) - mean * mean;
  float rstd = rsqrtf(var + 1e-6f);

  float sc[8], bi[8], dk[8];
  *(float4*)&sc[0] = ((const float4*)lns)[tid * 2];
  *(float4*)&sc[4] = ((const float4*)lns)[tid * 2 + 1];
  *(float4*)&bi[0] = ((const float4*)lnb)[tid * 2];
  *(float4*)&bi[4] = ((const float4*)lnb)[tid * 2 + 1];
  *(float4*)&dk[0] = ((const float4*)dtk)[tid * 2];
  *(float4*)&dk[4] = ((const float4*)dtk)[tid * 2 + 1];

  float dot = 0.f;
  s16x8 o;
#pragma unroll
  for (int j = 0; j < 8; ++j) {
    float xv = (v[j] - mean) * rstd * sc[j] + bi[j];
    xv = fminf(fmaxf(xv, -1.0e6f), 1.0e6f);
    dot += xv * dk[j];
    o[j] = (short)f2bf(xv);
  }
  *(s16x8*)(xn + (size_t)row * H_DIM + tid * 8) = o;

  __syncthreads();
#pragma unroll
  for (int off = 32; off; off >>= 1) dot += __shfl_down(dot, off);
  if ((tid & 63) == 0) red[tid >> 6] = dot;
  __syncthreads();
  if (tid == 0)
    delta[row] = __expf(red[0] + red[1] + red[2] + red[3] + dtb[0]);
}

// ---------------- chunked parallel scan ----------------
__global__ __launch_bounds__(256) void scan1_kernel(
    const unsigned short* __restrict__ U, const float* __restrict__ delta,
    const float* __restrict__ Adiag, float* __restrict__ Q, float* __restrict__ P)
{
  const int h = blockIdx.x * 1024 + threadIdx.x * 4;
  const int c = blockIdx.y, b = blockIdx.z;
  const float4 a = *(const float4*)(Adiag + h);
  const unsigned short* u = U + ((size_t)b * SEQ + c * CLEN) * H_DIM + h;
  const float* dl = delta + b * SEQ + c * CLEN;
  float4 st = {0.f, 0.f, 0.f, 0.f};
  float4 pr = {1.f, 1.f, 1.f, 1.f};
#pragma unroll 8
  for (int s = 0; s < CLEN; ++s) {
    const float d = dl[s];
    const ushort4 uv = *(const ushort4*)(u + (size_t)s * H_DIM);
    const float dx = __expf(d * a.x), dy = __expf(d * a.y);
    const float dz = __expf(d * a.z), dw = __expf(d * a.w);
    st.x = fmaf(st.x, dx, bf2f(uv.x)); st.y = fmaf(st.y, dy, bf2f(uv.y));
    st.z = fmaf(st.z, dz, bf2f(uv.z)); st.w = fmaf(st.w, dw, bf2f(uv.w));
    pr.x *= dx; pr.y *= dy; pr.z *= dz; pr.w *= dw;
  }
  const size_t idx = ((size_t)b * CCH + c) * H_DIM + h;
  *(float4*)(Q + idx) = st;
  *(float4*)(P + idx) = pr;
}

__global__ __launch_bounds__(256) void scan3_kernel(
    const unsigned short* __restrict__ U, const float* __restrict__ delta,
    const float* __restrict__ Adiag, const float* __restrict__ Q,
    const float* __restrict__ P, const float* __restrict__ ctx,
    unsigned short* __restrict__ states, float* __restrict__ finalSt)
{
  const int h = blockIdx.x * 1024 + threadIdx.x * 4;
  const int c = blockIdx.y, b = blockIdx.z;
  const float4 a = *(const float4*)(Adiag + h);

  float4 st = *(const float4*)(ctx + (size_t)b * H_DIM + h);
  for (int cc = 0; cc < c; ++cc) {
    const size_t idx = ((size_t)b * CCH + cc) * H_DIM + h;
    const float4 P4 = *(const float4*)(P + idx);
    const float4 Q4 = *(const float4*)(Q + idx);
    st.x = fmaf(st.x, P4.x, Q4.x); st.y = fmaf(st.y, P4.y, Q4.y);
    st.z = fmaf(st.z, P4.z, Q4.z); st.w = fmaf(st.w, P4.w, Q4.w);
  }

  const unsigned short* u = U + ((size_t)b * SEQ + c * CLEN) * H_DIM + h;
  unsigned short* so = states + ((size_t)b * SEQ + c * CLEN) * H_DIM + h;
  const float* dl = delta + b * SEQ + c * CLEN;
#pragma unroll 8
  for (int s = 0; s < CLEN; ++s) {
    const float d = dl[s];
    const ushort4 uv = *(const ushort4*)(u + (size_t)s * H_DIM);
    const float dx = __expf(d * a.x), dy = __expf(d * a.y);
    const float dz = __expf(d * a.z), dw = __expf(d * a.w);
    st.x = fmaf(st.x, dx, bf2f(uv.x)); st.y = fmaf(st.y, dy, bf2f(uv.y));
    st.z = fmaf(st.z, dz, bf2f(uv.z)); st.w = fmaf(st.w, dw, bf2f(uv.w));
    ushort4 ov = { f2bf(st.x), f2bf(st.y), f2bf(st.z), f2bf(st.w) };
    *(ushort4*)(so + (size_t)s * H_DIM) = ov;
  }
  if (c == CCH - 1)
    *(float4*)(finalSt + (size_t)b * H_DIM + h) = st;
}

// ===== 256x256 8-phase bf16 GEMM, SINGLE barrier/phase + sparse vmcnt =====
// Phase = {reads(this phase); stage; MFMA(compiler-counted lgkm); [vmcnt(6)
// at P4/P8]; s_barrier}. One barrier/phase lets early waves' MFMA overlap
// late waves' ds_reads (LDS pipe || MFMA pipe). WAR safe: each stage's
// target region last read a phase ago (reads complete before their QMM via
// data-dep, barrier follows). RAW: FIFO drain at P4 covers buf1's 4 halves
// (14->6 = oldest 8), at P8 covers buf0's (verified); epilogue drains to 0.
// EPI: 1 = bf16 out, 2 = GLU: out = Y * sigmoid(acc + gbias)  (f32 out)

#define BARR()  __builtin_amdgcn_s_barrier();
#define VMC(N)  asm volatile("s_waitcnt vmcnt(" #N ")" ::: "memory");

#define RD_A(DST, PL, PHH, OFF) { _Pragma("unroll") for (int i_ = 0; i_ < 4; ++i_) { \
    DST[0][i_] = *(const s16x8*)((PL) + (OFF) + i_ * 4096); \
    DST[1][i_] = *(const s16x8*)((PHH) + (OFF) + i_ * 4096); } }
#define RD_B(DST, PL, PHH, OFF) { _Pragma("unroll") for (int j_ = 0; j_ < 2; ++j_) { \
    DST[0][j_] = *(const s16x8*)((PL) + (OFF) + j_ * 8192); \
    DST[1][j_] = *(const s16x8*)((PHH) + (OFF) + j_ * 8192); } }

#define QMM(IB, JB, AF, BF) { __builtin_amdgcn_s_setprio(1); \
  _Pragma("unroll") for (int i_ = 0; i_ < 4; ++i_) \
  _Pragma("unroll") for (int j_ = 0; j_ < 2; ++j_) { \
    acc[(IB)+i_][(JB)+j_] = __builtin_amdgcn_mfma_f32_16x16x32_bf16(AF[0][i_], BF[0][j_], acc[(IB)+i_][(JB)+j_], 0, 0, 0); \
    acc[(IB)+i_][(JB)+j_] = __builtin_amdgcn_mfma_f32_16x16x32_bf16(AF[1][i_], BF[1][j_], acc[(IB)+i_][(JB)+j_], 0, 0, 0); } \
  __builtin_amdgcn_s_setprio(0); }

#define STAGE_A(BUF, HH, TT) { const char* s_ = srcA + (HH) * 524288 + (TT) * 128; \
  char* d_ = ldsA + (BUF) * 32768 + (HH) * 16384 + tid16; \
  gl_lds16(s_, d_); gl_lds16(s_ + 262144, d_ + 8192); }
#define STAGE_B(BUF, HH, TT) { const char* s_ = srcB + (HH) * 524288 + (TT) * 128; \
  char* d_ = ldsB + (BUF) * 32768 + (HH) * 16384 + tid16; \
  gl_lds16(s_, d_); gl_lds16(s_ + 262144, d_ + 8192); }

template <int EPI>
__global__ __launch_bounds__(512, 2) void gemm8p(
    const char* __restrict__ Ab, const char* __restrict__ Bb,
    float* __restrict__ outF, unsigned short* __restrict__ outH,
    const unsigned short* __restrict__ Ybf, const float* __restrict__ gbias)
{
  extern __shared__ char lds[];
  char* ldsA = lds;            // 2 bufs x 32KB
  char* ldsB = lds + 65536;    // 2 bufs x 32KB

  const int tid  = threadIdx.x;
  const int lane = tid & 63, wid = tid >> 6;
  const int wr = wid >> 2, wc = wid & 3;       // 2x4 wave grid
  const int fr = lane & 15, kq = lane >> 4;

  // ---- XCD-grouped block swizzle: each XCD owns an 8(bm) x 4(bn) group ----
  const int bid = blockIdx.x;
  const int xcd = bid & 7;
  const int li  = bid >> 3;
  const int bm  = (xcd >> 1) * 8 + (li & 7);
  const int bn  = (xcd & 1) * 4 + (li >> 3);

  // ---- staging source (pre-swizzled global, linear LDS dest) ----
  const int grow = tid >> 3;
  const int gswz = ((tid & 7) ^ (grow & 7)) << 4;
  const char* srcA = Ab + ((size_t)(bm * 256 + grow)) * 4096 + gswz;
  const char* srcB = Bb + ((size_t)(bn * 256 + grow)) * 4096 + gswz;
  const int tid16 = tid << 4;

  // ---- swizzled ds_read base pointers ----
  const int sw0 = ((kq ^ (fr & 7)) << 4);
  const int sw1 = (((4 | kq) ^ (fr & 7)) << 4);
  const char* pa0b0 = ldsA + wr * 2048 + fr * 128 + sw0;
  const char* pa1b0 = ldsA + wr * 2048 + fr * 128 + sw1;
  const char* pa0b1 = pa0b0 + 32768;
  const char* pa1b1 = pa1b0 + 32768;
  const char* pb0b0 = ldsB + wc * 2048 + fr * 128 + sw0;
  const char* pb1b0 = ldsB + wc * 2048 + fr * 128 + sw1;
  const char* pb0b1 = pb0b0 + 32768;
  const char* pb1b1 = pb1b0 + 32768;

  f32x4 acc[8][4] = {};
  s16x8 a03[2][4], a47[2][4], b01[2][2], b23[2][2];

  // ---- prologue (vmcnt(4) after 4 halves, vmcnt(6) after +3) ----
  STAGE_A(0, 0, 0); STAGE_B(0, 0, 0); STAGE_B(0, 1, 0); STAGE_A(0, 1, 0);
  VMC(4);
  STAGE_A(1, 0, 1); STAGE_B(1, 0, 1); STAGE_B(1, 1, 1);
  VMC(6);
  BARR();

  // ---- main loop: 15 iters x 2 K-tiles (tiles 0..29) ----
  for (int t = 0; t < NKT / 2 - 1; ++t) {
    const int T0 = 2 * t;
    // P1: 12 reads; stage A1h1(T0+1)
    RD_A(a03, pa0b0, pa1b0, 0);
    RD_B(b01, pb0b0, pb1b0, 0);
    STAGE_A(1, 1, T0 + 1);
    QMM(0, 0, a03, b01); BARR();
    // P2: 4 reads; stage A0h0(T0+2)
    RD_B(b23, pb0b0, pb1b0, 16384);
    STAGE_A(0, 0, T0 + 2);
    QMM(0, 2, a03, b23); BARR();
    // P3: 8 reads; stage B0h0(T0+2)
    RD_A(a47, pa0b0, pa1b0, 16384);
    STAGE_B(0, 0, T0 + 2);
    QMM(4, 0, a47, b01); BARR();
    // P4: stage B0h1(T0+2); counted vmcnt certifies buf1(T0+1)
    STAGE_B(0, 1, T0 + 2);
    QMM(4, 2, a47, b23); VMC(6); BARR();
    // P5: buf1 reads; stage A0h1(T0+2)
    RD_A(a03, pa0b1, pa1b1, 0);
    RD_B(b01, pb0b1, pb1b1, 0);
    STAGE_A(0, 1, T0 + 2);
    QMM(0, 0, a03, b01); BARR();
    // P6: stage A1h0(T0+3)
    RD_B(b23, pb0b1, pb1b1, 16384);
    STAGE_A(1, 0, T0 + 3);
    QMM(0, 2, a03, b23); BARR();
    // P7: stage B1h0(T0+3)
    RD_A(a47, pa0b1, pa1b1, 16384);
    STAGE_B(1, 0, T0 + 3);
    QMM(4, 0, a47, b01); BARR();
    // P8: stage B1h1(T0+3); counted vmcnt certifies buf0(T0+2)
    STAGE_B(1, 1, T0 + 3);
    QMM(4, 2, a47, b23); VMC(6); BARR();
  }

  // ---- epilogue: tiles 30 (buf0) and 31 (buf1) ----
  RD_A(a03, pa0b0, pa1b0, 0);
  RD_B(b01, pb0b0, pb1b0, 0);
  STAGE_A(1, 1, 31);
  QMM(0, 0, a03, b01); BARR();
  RD_B(b23, pb0b0, pb1b0, 16384);
  QMM(0, 2, a03, b23); BARR();
  RD_A(a47, pa0b0, pa1b0, 16384);
  QMM(4, 0, a47, b01); BARR();
  QMM(4, 2, a47, b23); VMC(0); BARR();
  RD_A(a03, pa0b1, pa1b1, 0);
  RD_B(b01, pb0b1, pb1b1, 0);
  QMM(0, 0, a03, b01);
  RD_B(b23, pb0b1, pb1b1, 16384);
  QMM(0, 2, a03, b23);
  RD_A(a47, pa0b1, pa1b1, 16384);
  QMM(4, 0, a47, b01);
  QMM(4, 2, a47, b23);

  // ---- LDS-staged coalesced C write ----
  __syncthreads();
  const int cr = (lane >> 4) << 2;
  const int cc = lane & 15;
  if constexpr (EPI == 1) {
#pragma unroll
    for (int i = 0; i < 8; ++i)
#pragma unroll
      for (int j = 0; j < 4; ++j)
#pragma unroll
        for (int r = 0; r < 4; ++r) {
          const int row = (2 * i + wr) * 16 + cr + r;
          const int col = (4 * j + wc) * 16 + cc;
          const int off = (row * 512 + col * 2) ^ ((row & 7) << 4);
          *(unsigned short*)(lds + off) = f2bf(acc[i][j][r]);
        }
    __syncthreads();
#pragma unroll
    for (int it = 0; it < 16; ++it) {
      const int L = it * 8192 + tid * 16;
      const int row = L >> 9, inrow = L & 511;
      const s16x8 v = *(const s16x8*)(lds + (L ^ ((row & 7) << 4)));
      *(s16x8*)(outH + ((size_t)(bm * 256 + row)) * H_DIM + bn * 256 + (inrow >> 1)) = v;
    }
  } else {
#pragma unroll
    for (int p = 0; p < 2; ++p) {
      if (p) __syncthreads();
#pragma unroll
      for (int i = 4 * p; i < 4 * p + 4; ++i)
#pragma unroll
        for (int j = 0; j < 4; ++j)
#pragma unroll
          for (int r = 0; r < 4; ++r) {
            const int lrow = (2 * i + wr) * 16 + cr + r - 128 * p;
            const int col = (4 * j + wc) * 16 + cc;
            const int off = (lrow * 1024 + col * 4) ^ ((lrow & 7) << 4);
            *(float*)(lds + off) = acc[i][j][r];
          }
      __syncthreads();
#pragma unroll
      for (int it = 0; it < 16; ++it) {
        const int L = it * 8192 + tid * 16;
        const int lrow = L >> 10, inrow = L & 1023;
        const f32x4 v = *(const f32x4*)(lds + (L ^ ((lrow & 7) << 4)));
        const size_t growg = (size_t)(bm * 256 + 128 * p + lrow);
        const int gcol = bn * 256 + (inrow >> 2);
        const float4 gb4 = *(const float4*)(gbias + gcol);
        const ushort4 y4 = *(const ushort4*)(Ybf + growg * H_DIM + gcol);
        float4 o;
        o.x = bf2f(y4.x) / (1.f + __expf(-(v[0] + gb4.x)));
        o.y = bf2f(y4.y) / (1.f + __expf(-(v[1] + gb4.y)));
        o.z = bf2f(y4.z) / (1.f + __expf(-(v[2] + gb4.z)));
        o.w = bf2f(y4.w) / (1.f + __expf(-(v[3] + gb4.w)));
        *(float4*)(outF + growg * H_DIM + gcol) = o;
      }
    }
  }
}

extern "C" void kernel_launch(void* const* d_in, const int* in_sizes, int n_in,
                              void* d_out, int out_size, void* d_ws, size_t ws_size,
                              hipStream_t stream) {
  (void)in_sizes; (void)n_in; (void)out_size; (void)ws_size;
  const float* x     = (const float*)d_in[0];
  const float* ctx   = (const float*)d_in[1];
  const float* Adiag = (const float*)d_in[2];
  const float* Bm    = (const float*)d_in[3];
  const float* Cm    = (const float*)d_in[4];
  const float* dtk   = (const float*)d_in[5];
  const float* dtb   = (const float*)d_in[6];
  const float* gk    = (const float*)d_in[7];
  const float* gb    = (const float*)d_in[8];
  const float* lns   = (const float*)d_in[9];
  const float* lnb   = (const float*)d_in[10];
  float* outF = (float*)d_out;

  char* ws = (char*)d_ws;
  unsigned short* xnY    = (unsigned short*)ws; ws += (size_t)M_DIM * H_DIM * 2;  // xn, later Y
  unsigned short* U      = (unsigned short*)ws; ws += (size_t)M_DIM * H_DIM * 2;
  unsigned short* states = (unsigned short*)ws; ws += (size_t)M_DIM * H_DIM * 2;
  unsigned short* T1     = (unsigned short*)ws; ws += (size_t)H_DIM * H_DIM * 2;
  unsigned short* T2     = (unsigned short*)ws; ws += (size_t)H_DIM * H_DIM * 2;
  unsigned short* T3     = (unsigned short*)ws; ws += (size_t)H_DIM * H_DIM * 2;
  float* delta           = (float*)ws;          ws += (size_t)M_DIM * 4;
  float* Qbuf            = (float*)ws;          ws += (size_t)B_SZ * CCH * H_DIM * 4;
  float* Pbuf            = (float*)ws;          ws += (size_t)B_SZ * CCH * H_DIM * 4;

  hipFuncSetAttribute((const void*)&gemm8p<1>,
                      hipFuncAttributeMaxDynamicSharedMemorySize, 131072);
  hipFuncSetAttribute((const void*)&gemm8p<2>,
                      hipFuncAttributeMaxDynamicSharedMemorySize, 131072);

  dim3 tb(256);
  pre_kernel<<<12288 + M_DIM, tb, 0, stream>>>(
      Bm, T1, Cm, T2, gk, T3, x, lns, lnb, dtk, dtb, xnY, delta);
  gemm8p<1><<<256, 512, 131072, stream>>>(
      (const char*)xnY, (const char*)T1, nullptr, U, nullptr, nullptr);
  scan1_kernel<<<dim3(H_DIM / 1024, CCH, B_SZ), tb, 0, stream>>>(
      U, delta, Adiag, Qbuf, Pbuf);
  scan3_kernel<<<dim3(H_DIM / 1024, CCH, B_SZ), tb, 0, stream>>>(
      U, delta, Adiag, Qbuf, Pbuf, ctx, states, outF + (size_t)M_DIM * H_DIM);
  gemm8p<1><<<256, 512, 131072, stream>>>(
      (const char*)states, (const char*)T2, nullptr, xnY, nullptr, nullptr);
  gemm8p<2><<<256, 512, 131072, stream>>>(
      (const char*)xnY, (const char*)T3, outF, nullptr, xnY, gb);
}